// Round 13
// baseline (278.104 us; speedup 1.0000x reference)
//
#include <hip/hip_runtime.h>
#include <stdint.h>

#define B_ 2
#define S_ 2048
#define D_ 2048
#define H_ 16
#define KVH_ 4
#define HD_ 128
#define ROT_ 64
#define WINDOW_ 1024
#define EPS_ 1e-6f
#define M_ (B_ * S_)
#define NQKV_ 3072

#define QBLK 128
#define KVBLK 32
#define LOG2E 1.44269504088896340736f
#define DEFER_THR 8.0f

typedef unsigned short ushort_t;
typedef _Float16 f16;
typedef float f32x4 __attribute__((ext_vector_type(4)));
typedef float f32x16 __attribute__((ext_vector_type(16)));
typedef f16 f16x4 __attribute__((ext_vector_type(4)));
typedef f16 f16x8 __attribute__((ext_vector_type(8)));

#define NINF (-__builtin_inff())
#define EXP2F(x) __builtin_exp2f(x)

// async global->LDS, 16B per lane. dst must be wave-uniform; HW adds lane*16.
__device__ __forceinline__ void gload16(const void* g, void* l) {
  __builtin_amdgcn_global_load_lds(
      (const __attribute__((address_space(1))) void*)g,
      (__attribute__((address_space(3))) void*)l, 16, 0, 0);
}

// pack 2 f32 -> 1 u32 of 2 fp16 (rtz)
__device__ __forceinline__ int cvtpk_i(float a, float b) {
  auto h = __builtin_amdgcn_cvt_pkrtz(a, b);
  int r; __builtin_memcpy(&r, &h, 4); return r;
}

// ---------------- cast x (f32 -> f16), 8 elems/thread ----------------
__launch_bounds__(256, 4)
__global__ void cast_f32_f16(const float* __restrict__ src, f16* __restrict__ dst, int n8) {
  int i = blockIdx.x * 256 + threadIdx.x;
  if (i >= n8) return;
  float4 a = reinterpret_cast<const float4*>(src)[i * 2];
  float4 b = reinterpret_cast<const float4*>(src)[i * 2 + 1];
  f16x8 o = { (f16)a.x, (f16)a.y, (f16)a.z, (f16)a.w,
              (f16)b.x, (f16)b.y, (f16)b.z, (f16)b.w };
  reinterpret_cast<f16x8*>(dst)[i] = o;
}

// ---------------- transpose f32 [R][C] -> f16 [C][R] ----------------
__launch_bounds__(256, 4)
__global__ void transpose_f32_f16(const float* __restrict__ src, f16* __restrict__ dst,
                                  int R, int C) {
  __shared__ float tile[32][33];
  int c0 = blockIdx.x * 32, r0 = blockIdx.y * 32;
  int tx = threadIdx.x & 31, ty = threadIdx.x >> 5;
#pragma unroll
  for (int i = 0; i < 32; i += 8)
    tile[ty + i][tx] = src[(size_t)(r0 + ty + i) * C + c0 + tx];
  __syncthreads();
#pragma unroll
  for (int i = 0; i < 32; i += 8)
    dst[(size_t)(c0 + ty + i) * R + r0 + tx] = (f16)tile[tx][ty + i];
}

// ---------------- batched transpose 16-bit [R][C] -> [C][R] ----------------
__launch_bounds__(256, 4)
__global__ void transpose16(const ushort_t* __restrict__ src, ushort_t* __restrict__ dst,
                            int R, int C) {
  __shared__ ushort_t tile[32][33];
  size_t base = (size_t)blockIdx.z * R * C;
  src += base; dst += base;
  int c0 = blockIdx.x * 32, r0 = blockIdx.y * 32;
  int tx = threadIdx.x & 31, ty = threadIdx.x >> 5;
#pragma unroll
  for (int i = 0; i < 32; i += 8)
    tile[ty + i][tx] = src[(size_t)(r0 + ty + i) * C + c0 + tx];
  __syncthreads();
#pragma unroll
  for (int i = 0; i < 32; i += 8)
    dst[(size_t)(c0 + ty + i) * R + r0 + tx] = tile[tx][ty + i];
}

// ---------------- fp16 GEMM: single-buffered m97 structure, templated output ----
template<typename OT>
__launch_bounds__(256, 2)
__global__ void gemm_f16(const f16* __restrict__ A, const f16* __restrict__ Bt,
                         OT* __restrict__ C, int M, int N, int K) {
  __shared__ __attribute__((aligned(16))) f16 As[128][64];
  __shared__ __attribute__((aligned(16))) f16 Bs[128][64];
  const int gx = gridDim.x;
  const int nwg = gx * gridDim.y;
  const int flat = blockIdx.y * gx + blockIdx.x;
  const int q8 = nwg >> 3;
  const int id2 = (flat & 7) * q8 + (flat >> 3);
  const int bm = (id2 / gx) * 128, bn = (id2 % gx) * 128;
  const int tid = threadIdx.x;
  const int lane = tid & 63, wid = tid >> 6;
  const int wm = (wid >> 1) * 64, wn = (wid & 1) * 64;
  const int rr = lane & 15, rg = lane >> 4;
  const int sw = (((lane & 7) ^ (lane >> 3)) << 4);
  const int srw = lane >> 3;
  const char* Ab = (const char*)A + ((size_t)(bm + wid * 32 + srw) * K) * 2 + sw;
  const char* Bb = (const char*)Bt + ((size_t)(bn + wid * 32 + srw) * K) * 2 + sw;
  f32x4 acc[4][4] = {};
  for (int k0 = 0; k0 < K; k0 += 64) {
    __syncthreads();   // WAR: all waves done reading previous tile
#pragma unroll
    for (int g = 0; g < 4; ++g) {
      gload16(Ab + (size_t)(g * 8) * K * 2 + (size_t)k0 * 2,
              (char*)&As[0][0] + (wid * 32 + g * 8) * 128);
      gload16(Bb + (size_t)(g * 8) * K * 2 + (size_t)k0 * 2,
              (char*)&Bs[0][0] + (wid * 32 + g * 8) * 128);
    }
    __syncthreads();   // RAW: barrier drains vmcnt -> staged data visible
    f16x8 af[4][2], bf[4][2];
#pragma unroll
    for (int i = 0; i < 4; ++i)
#pragma unroll
      for (int kk = 0; kk < 2; ++kk) {
        af[i][kk] = *reinterpret_cast<const f16x8*>(
            (const char*)&As[0][0] + (wm + i * 16 + rr) * 128 +
            ((kk * 64 + rg * 16) ^ ((rr & 7) << 4)));
        bf[i][kk] = *reinterpret_cast<const f16x8*>(
            (const char*)&Bs[0][0] + (wn + i * 16 + rr) * 128 +
            ((kk * 64 + rg * 16) ^ ((rr & 7) << 4)));
      }
#pragma unroll
    for (int kk = 0; kk < 2; ++kk)
#pragma unroll
      for (int i = 0; i < 4; ++i)
#pragma unroll
        for (int j = 0; j < 4; ++j)
          acc[i][j] = __builtin_amdgcn_mfma_f32_16x16x32_f16(af[i][kk], bf[j][kk],
                                                             acc[i][j], 0, 0, 0);
  }
#pragma unroll
  for (int i = 0; i < 4; ++i)
#pragma unroll
    for (int j = 0; j < 4; ++j)
#pragma unroll
      for (int r = 0; r < 4; ++r)
        C[(size_t)(bm + wm + i * 16 + rg * 4 + r) * N + (bn + wn + j * 16 + rr)] =
            (OT)acc[i][j][r];
}

// ---------------- RMSNorm + RoPE for K and V, f16 in / f16 out ----------------
// K is pre-scaled by LOG2E so QK^T logits are in log2 units.
__launch_bounds__(256, 4)
__global__ void norm_rope_kv(const f16* __restrict__ qkv, const float* __restrict__ cosb,
                             const float* __restrict__ sinb, const float* __restrict__ ksc,
                             f16* __restrict__ kf, f16* __restrict__ vb) {
  int gw = blockIdx.x * 4 + (threadIdx.x >> 6);
  int lane = threadIdx.x & 63;
  int row = gw >> 3, c = gw & 7;
  int b = row >> 11, s = row & (S_ - 1);
  int col = (c < 4) ? (2048 + c * 128) : (2560 + (c - 4) * 128);
  const f16* src = qkv + (size_t)row * NQKV_ + col;
  unsigned int u = *reinterpret_cast<const unsigned int*>(src + lane * 2);
  f16 p2[2]; __builtin_memcpy(p2, &u, 4);
  float vx = (float)p2[0], vy = (float)p2[1];
  float ss = vx * vx + vy * vy;
#pragma unroll
  for (int off = 32; off; off >>= 1) ss += __shfl_xor(ss, off);
  float inv = rsqrtf(ss * (1.0f / HD_) + EPS_);
  float x0 = vx * inv, x1 = vy * inv;
  int d0 = lane * 2;
  f16* dst;
  size_t idx;
  if (c < 4) {  // k: (1+scale) then rope on dims [0,64), then *LOG2E
    x0 *= (1.0f + ksc[d0]);
    x1 *= (1.0f + ksc[d0 + 1]);
    float y0 = __shfl_xor(x0, 16);
    float y1 = __shfl_xor(x1, 16);
    if (d0 < ROT_) {
      int dm = d0 & 31;
      float cs0 = cosb[s * 32 + dm],     sn0 = sinb[s * 32 + dm];
      float cs1 = cosb[s * 32 + dm + 1], sn1 = sinb[s * 32 + dm + 1];
      if (d0 < 32) { x0 = x0 * cs0 - y0 * sn0; x1 = x1 * cs1 - y1 * sn1; }
      else         { x0 = x0 * cs0 + y0 * sn0; x1 = x1 * cs1 + y1 * sn1; }
    }
    x0 *= LOG2E; x1 *= LOG2E;
    dst = kf; idx = ((size_t)((b * KVH_ + c) * S_ + s)) * HD_ + d0;
  } else {      // v: plain rmsnorm
    dst = vb; idx = ((size_t)((b * KVH_ + (c - 4)) * S_ + s)) * HD_ + d0;
  }
  f16 o[2] = { (f16)x0, (f16)x1 };
  unsigned int pk; __builtin_memcpy(&pk, o, 4);
  *reinterpret_cast<unsigned int*>(dst + idx) = pk;
}

// ---------------- flash attention v9: swapped QK^T, KVBLK=32, 4 blocks/CU --------
// 512 blocks x 256 thr (4 waves x 32 q-rows). LDS 32 KB (dbuf K 8KB + V 8KB tiles)
// -> ~4 blocks/CU for cross-block latency hiding. Swapped 32x32 MFMA QK^T,
// in-register softmax (T12 cvt_pk+permlane32_swap), defer-max, log2 domain.
__launch_bounds__(256, 4)
__global__ void flash_attn(const f16* __restrict__ qkv, const float* __restrict__ cosb,
                           const float* __restrict__ sinb, const float* __restrict__ qsc,
                           const f16* __restrict__ kfp, const f16* __restrict__ vt,
                           f16* __restrict__ ctxf) {
  __shared__ __attribute__((aligned(16))) f16 Ks[2][KVBLK][128];   // 16 KB
  __shared__ __attribute__((aligned(16))) f16 Vs[2][128][KVBLK];   // 16 KB
  const int id = blockIdx.x;
  const int g8 = id & 7, rest = id >> 3;          // rest in [0,64)
  const int b = g8 >> 2, kvh = g8 & 3;
  int hh, qtile;
  if (rest < 32) { hh = rest >> 3; qtile = 8 + (rest & 7); }     // heavy: 36 tiles
  else { int lv = rest - 32; hh = lv >> 3; qtile = lv & 7; }     // light: 4..32
  const int h = kvh * 4 + hh;
  const int lane = threadIdx.x & 63, w = threadIdx.x >> 6;
  const int ql = lane & 31;          // this lane's q column
  const int hi = lane >> 5;          // half (0/1)
  const int qBase = qtile * QBLK;
  const int qw = qBase + w * 32;
  const int q = qw + ql;             // sequence position
  const f16* Kh = kfp + (size_t)(b * KVH_ + kvh) * S_ * HD_;
  const f16* Vh = vt  + (size_t)(b * KVH_ + kvh) * HD_ * S_;

  // ---- q prep: lane loads 64 f16 of row q (d = kk*16 + hi*8 + j), rmsnorm,
  //      scale, rope (lane-local pairs kk<->kk+2), cvt to B-frag layout ----
  f16x8 qf[8];
  {
    const f16* qrow = qkv + (size_t)(b * S_ + q) * NQKV_ + h * HD_;
    float qv[8][8];
    float ssq = 0.f;
#pragma unroll
    for (int kk = 0; kk < 8; ++kk) {
      f16x8 u = *reinterpret_cast<const f16x8*>(qrow + kk * 16 + hi * 8);
#pragma unroll
      for (int j = 0; j < 8; ++j) {
        qv[kk][j] = (float)u[j];
        ssq += qv[kk][j] * qv[kk][j];
      }
    }
    ssq += __shfl_xor(ssq, 32);   // partner lane has the other 64 dims
    float inv = rsqrtf(ssq * (1.0f / HD_) + EPS_);
#pragma unroll
    for (int kk = 0; kk < 8; ++kk)
#pragma unroll
      for (int j = 0; j < 8; ++j)
        qv[kk][j] *= inv * (1.0f + qsc[kk * 16 + hi * 8 + j]);
    const float* cs = cosb + (size_t)q * 32;
    const float* sn = sinb + (size_t)q * 32;
#pragma unroll
    for (int kk = 0; kk < 2; ++kk)
#pragma unroll
      for (int j = 0; j < 8; ++j) {
        int d = kk * 16 + hi * 8 + j;          // in [0,32)
        float c = cs[d], s_ = sn[d];
        float x0 = qv[kk][j], x1 = qv[kk + 2][j];
        qv[kk][j]     = x0 * c - x1 * s_;
        qv[kk + 2][j] = x1 * c + x0 * s_;
      }
#pragma unroll
    for (int kk = 0; kk < 8; ++kk)
#pragma unroll
      for (int j = 0; j < 8; ++j)
        qf[kk][j] = (f16)qv[kk][j];
  }

  f32x16 acc[4] = {};
  float m_run = NINF, msafe = 0.f, l_run = 0.f;

  int kvStart = qBase - (WINDOW_ - 1);
  if (kvStart < 0) kvStart = 0;
  kvStart &= ~(KVBLK - 1);
  const int ntile = (qBase + QBLK - kvStart) >> 5;

  // staging lane mapping: K 8 rows/wave (4 per issue), V 32 d-rows/wave (16 per issue)
  const int k_r0 = lane >> 4;          // 0..3
  const int k_cb = (lane & 15) * 16;
  const int v_r0 = lane >> 2;          // 0..15
  const int v_cb = (lane & 3) * 16;

#define STAGE(bufs, key0_)                                                           \
  do {                                                                               \
    _Pragma("unroll")                                                                \
    for (int gg = 0; gg < 2; ++gg) {                                                 \
      int krow = gg * 4 + k_r0;                                                      \
      gload16((const char*)Kh + (size_t)((key0_) + w * 8 + krow) * 256 +             \
                  (k_cb ^ ((krow & 7) << 4)),                                        \
              (char*)&Ks[bufs][0][0] + (w * 8 + gg * 4) * 256);                      \
      int vrow = gg * 16 + v_r0;                                                     \
      gload16((const char*)Vh + (size_t)(w * 32 + vrow) * (S_ * 2) +                 \
                  (size_t)(key0_) * 2 + (v_cb ^ ((vrow & 3) << 4)),                  \
              (char*)&Vs[bufs][0][0] + (w * 32 + gg * 16) * 64);                     \
    }                                                                                \
  } while (0)

  STAGE(0, kvStart);
  __syncthreads();

  for (int t = 0; t < ntile; ++t) {
    const int key0 = kvStart + t * KVBLK;
    const int buf = t & 1;
    if (t + 1 < ntile) STAGE(buf ^ 1, key0 + KVBLK);

    const bool live = (key0 <= qw + 31) && (key0 + 31 >= qw - (WINDOW_ - 1));
    if (live) {
      // ---- QK^T swapped: S^T[key][q], lane holds q=ql, 16 keys in regs ----
      f32x16 st;
      {
        const int rt = ql;
        const char* kbase = (const char*)&Ks[buf][0][0] + rt * 256;
        const int swz = (rt & 7) << 4;
        f32x16 s = {};
#pragma unroll
        for (int kk = 0; kk < 8; ++kk) {
          f16x8 kfr = *reinterpret_cast<const f16x8*>(kbase + ((kk * 32 + hi * 16) ^ swz));
          s = __builtin_amdgcn_mfma_f32_32x32x16_f16(kfr, qf[kk], s, 0, 0, 0);
        }
        st = s;
      }

      // ---- mask (skipped for interior tiles); key = key0+(r&3)+8(r>>2)+4hi ----
      const bool interior = (key0 + 31 <= qw) && (key0 >= qw - 992);
      if (!interior) {
#pragma unroll
        for (int r = 0; r < 16; ++r) {
          int kj = key0 + ((r & 3) + 8 * (r >> 2) + 4 * hi);
          bool valid = (kj <= q) && (q - kj < WINDOW_);
          if (!valid) st[r] = NINF;
        }
      }

      // ---- in-lane row max + one cross-half swap ----
      float tm = st[0];
#pragma unroll
      for (int r = 1; r < 16; ++r) tm = fmaxf(tm, st[r]);
      tm = fmaxf(tm, __shfl_xor(tm, 32));

      // ---- defer-max rescale ----
      bool defer = (tm - m_run <= DEFER_THR);
      if (!__all(defer)) {
        float mn = fmaxf(m_run, tm);
        float alpha = (m_run == NINF) ? 0.f : EXP2F(m_run - mn);
        m_run = mn;
        msafe = (mn == NINF) ? 0.f : mn;
#pragma unroll
        for (int dt = 0; dt < 4; ++dt)
#pragma unroll
          for (int r = 0; r < 16; ++r) acc[dt][r] *= alpha;
        l_run *= alpha;
      }
      // ---- exp (log2 domain) + row-sum ----
      float ps = 0.f;
#pragma unroll
      for (int r = 0; r < 16; ++r) {
        float p = EXP2F(st[r] - msafe);
        st[r] = p;
        ps += p;
      }
      ps += __shfl_xor(ps, 32);
      l_run += ps;

      // ---- P -> B-fragments in-register (cvt_pk + permlane32_swap) ----
      f16x8 pf[2];
#pragma unroll
      for (int ks = 0; ks < 2; ++ks) {
        const int rb = ks * 8;
        int w0 = cvtpk_i(st[rb + 0], st[rb + 1]);
        int w2 = cvtpk_i(st[rb + 4], st[rb + 5]);
        asm volatile("v_permlane32_swap_b32 %0, %1" : "+v"(w0), "+v"(w2));
        int w1 = cvtpk_i(st[rb + 2], st[rb + 3]);
        int w3 = cvtpk_i(st[rb + 6], st[rb + 7]);
        asm volatile("v_permlane32_swap_b32 %0, %1" : "+v"(w1), "+v"(w3));
        int wi[4] = { w0, w1, w2, w3 };
        __builtin_memcpy(&pf[ks], wi, 16);
      }

      // ---- PV swapped: ctx^T[d][q] += V^T-frag x P^T-frag ----
      __builtin_amdgcn_s_setprio(1);
#pragma unroll
      for (int dt = 0; dt < 4; ++dt) {
        const int d = dt * 32 + ql;
        const char* vbase = (const char*)&Vs[buf][0][0] + d * 64;
        const int swz = (d & 3) << 4;
#pragma unroll
        for (int ks = 0; ks < 2; ++ks) {
          f16x8 vf = *reinterpret_cast<const f16x8*>(vbase + ((ks * 32 + hi * 16) ^ swz));
          acc[dt] = __builtin_amdgcn_mfma_f32_32x32x16_f16(vf, pf[ks], acc[dt], 0, 0, 0);
        }
      }
      __builtin_amdgcn_s_setprio(0);
    }

    __syncthreads();   // drains prefetch vmcnt + all waves done with buf
  }
#undef STAGE

  // ---- epilogue: lane owns q; d = dt*32 + 8*g + 4*hi + r -> 8B packed stores ----
  const float rinv = 1.0f / l_run;
  f16* orow = ctxf + (size_t)(b * S_ + q) * D_ + h * HD_;
#pragma unroll
  for (int dt = 0; dt < 4; ++dt)
#pragma unroll
    for (int g = 0; g < 4; ++g) {
      f16x4 o;
#pragma unroll
      for (int r = 0; r < 4; ++r) o[r] = (f16)(acc[dt][g * 4 + r] * rinv);
      *reinterpret_cast<f16x4*>(orow + dt * 32 + 8 * g + 4 * hi) = o;
    }
}

extern "C" void kernel_launch(void* const* d_in, const int* in_sizes, int n_in,
                              void* d_out, int out_size, void* d_ws, size_t ws_size,
                              hipStream_t stream) {
  const float* x    = (const float*)d_in[0];
  // d_in[1] = mask (recomputed analytically)
  const float* cosb = (const float*)d_in[2];
  const float* sinb = (const float*)d_in[3];
  const float* Wq   = (const float*)d_in[4];
  const float* Wk   = (const float*)d_in[5];
  const float* Wv   = (const float*)d_in[6];
  const float* Wo   = (const float*)d_in[7];
  const float* qsc  = (const float*)d_in[8];
  const float* ksc  = (const float*)d_in[9];
  float* out = (float*)d_out;

  char* ws = (char*)d_ws;
  const size_t MB = 1ull << 20;
  // [0,16)  xh fp16         -> after gemm0 reused: ctxf fp16
  // [16,28) wqkvT fp16      -> after gemm0 reused: kf[16,20) vb[20,24) vtb[24,28)
  // [28,36) woT fp16
  // [36,60) qkv fp16
  f16* xh    = (f16*)(ws + 0 * MB);
  f16* ctxf  = (f16*)(ws + 0 * MB);
  f16* wqkvT = (f16*)(ws + 16 * MB);
  f16* kf    = (f16*)(ws + 16 * MB);
  f16* vb    = (f16*)(ws + 20 * MB);
  f16* vtb   = (f16*)(ws + 24 * MB);
  f16* woT   = (f16*)(ws + 28 * MB);
  f16* qkvh  = (f16*)(ws + 36 * MB);

  cast_f32_f16<<<dim3(M_ * D_ / 8 / 256), 256, 0, stream>>>(x, xh, M_ * D_ / 8);
  transpose_f32_f16<<<dim3(64, 64), 256, 0, stream>>>(Wq, wqkvT, D_, 2048);
  transpose_f32_f16<<<dim3(16, 64), 256, 0, stream>>>(Wk, wqkvT + (size_t)2048 * D_, D_, 512);
  transpose_f32_f16<<<dim3(16, 64), 256, 0, stream>>>(Wv, wqkvT + (size_t)2560 * D_, D_, 512);
  transpose_f32_f16<<<dim3(64, 64), 256, 0, stream>>>(Wo, woT, D_, D_);
  gemm_f16<f16><<<dim3(NQKV_ / 128, M_ / 128), 256, 0, stream>>>(
      xh, wqkvT, qkvh, M_, NQKV_, D_);
  norm_rope_kv<<<dim3(M_ * 8 / 4), 256, 0, stream>>>(qkvh, cosb, sinb, ksc, kf, vb);
  transpose16<<<dim3(HD_ / 32, S_ / 32, B_ * KVH_), 256, 0, stream>>>(
      (const ushort_t*)vb, (ushort_t*)vtb, S_, HD_);
  flash_attn<<<dim3((S_ / QBLK) * H_ * B_), 256, 0, stream>>>(
      qkvh, cosb, sinb, qsc, kf, vtb, ctxf);
  gemm_f16<float><<<dim3(D_ / 128, M_ / 128), 256, 0, stream>>>(
      ctxf, woT, out, M_, D_, D_);
}

// Round 14
// 202.794 us; speedup vs baseline: 1.3714x; 1.3714x over previous
//
#include <hip/hip_runtime.h>
#include <stdint.h>

#define B_ 2
#define S_ 2048
#define D_ 2048
#define H_ 16
#define KVH_ 4
#define HD_ 128
#define ROT_ 64
#define WINDOW_ 1024
#define EPS_ 1e-6f
#define M_ (B_ * S_)
#define NQKV_ 3072

#define QBLK 128
#define KVBLK 64
#define LOG2E 1.44269504088896340736f
#define DEFER_THR 8.0f

typedef unsigned short ushort_t;
typedef _Float16 f16;
typedef float f32x4 __attribute__((ext_vector_type(4)));
typedef float f32x16 __attribute__((ext_vector_type(16)));
typedef f16 f16x4 __attribute__((ext_vector_type(4)));
typedef f16 f16x8 __attribute__((ext_vector_type(8)));

#define NINF (-__builtin_inff())
#define EXP2F(x) __builtin_exp2f(x)

// async global->LDS, 16B per lane. dst must be wave-uniform; HW adds lane*16.
__device__ __forceinline__ void gload16(const void* g, void* l) {
  __builtin_amdgcn_global_load_lds(
      (const __attribute__((address_space(1))) void*)g,
      (__attribute__((address_space(3))) void*)l, 16, 0, 0);
}

// pack 2 f32 -> 1 u32 of 2 fp16 (rtz)
__device__ __forceinline__ int cvtpk_i(float a, float b) {
  auto h = __builtin_amdgcn_cvt_pkrtz(a, b);
  int r; __builtin_memcpy(&r, &h, 4); return r;
}

// ---------------- cast x (f32 -> f16), 8 elems/thread ----------------
__launch_bounds__(256, 4)
__global__ void cast_f32_f16(const float* __restrict__ src, f16* __restrict__ dst, int n8) {
  int i = blockIdx.x * 256 + threadIdx.x;
  if (i >= n8) return;
  float4 a = reinterpret_cast<const float4*>(src)[i * 2];
  float4 b = reinterpret_cast<const float4*>(src)[i * 2 + 1];
  f16x8 o = { (f16)a.x, (f16)a.y, (f16)a.z, (f16)a.w,
              (f16)b.x, (f16)b.y, (f16)b.z, (f16)b.w };
  reinterpret_cast<f16x8*>(dst)[i] = o;
}

// ---------------- transpose f32 [R][C] -> f16 [C][R] ----------------
__launch_bounds__(256, 4)
__global__ void transpose_f32_f16(const float* __restrict__ src, f16* __restrict__ dst,
                                  int R, int C) {
  __shared__ float tile[32][33];
  int c0 = blockIdx.x * 32, r0 = blockIdx.y * 32;
  int tx = threadIdx.x & 31, ty = threadIdx.x >> 5;
#pragma unroll
  for (int i = 0; i < 32; i += 8)
    tile[ty + i][tx] = src[(size_t)(r0 + ty + i) * C + c0 + tx];
  __syncthreads();
#pragma unroll
  for (int i = 0; i < 32; i += 8)
    dst[(size_t)(c0 + ty + i) * R + r0 + tx] = (f16)tile[tx][ty + i];
}

// ---------------- batched transpose 16-bit [R][C] -> [C][R] ----------------
__launch_bounds__(256, 4)
__global__ void transpose16(const ushort_t* __restrict__ src, ushort_t* __restrict__ dst,
                            int R, int C) {
  __shared__ ushort_t tile[32][33];
  size_t base = (size_t)blockIdx.z * R * C;
  src += base; dst += base;
  int c0 = blockIdx.x * 32, r0 = blockIdx.y * 32;
  int tx = threadIdx.x & 31, ty = threadIdx.x >> 5;
#pragma unroll
  for (int i = 0; i < 32; i += 8)
    tile[ty + i][tx] = src[(size_t)(r0 + ty + i) * C + c0 + tx];
  __syncthreads();
#pragma unroll
  for (int i = 0; i < 32; i += 8)
    dst[(size_t)(c0 + ty + i) * R + r0 + tx] = tile[tx][ty + i];
}

// ---------------- fp16 GEMM: single-buffered m97 structure, templated output ----
template<typename OT>
__launch_bounds__(256, 2)
__global__ void gemm_f16(const f16* __restrict__ A, const f16* __restrict__ Bt,
                         OT* __restrict__ C, int M, int N, int K) {
  __shared__ __attribute__((aligned(16))) f16 As[128][64];
  __shared__ __attribute__((aligned(16))) f16 Bs[128][64];
  const int gx = gridDim.x;
  const int nwg = gx * gridDim.y;
  const int flat = blockIdx.y * gx + blockIdx.x;
  const int q8 = nwg >> 3;
  const int id2 = (flat & 7) * q8 + (flat >> 3);
  const int bm = (id2 / gx) * 128, bn = (id2 % gx) * 128;
  const int tid = threadIdx.x;
  const int lane = tid & 63, wid = tid >> 6;
  const int wm = (wid >> 1) * 64, wn = (wid & 1) * 64;
  const int rr = lane & 15, rg = lane >> 4;
  const int sw = (((lane & 7) ^ (lane >> 3)) << 4);
  const int srw = lane >> 3;
  const char* Ab = (const char*)A + ((size_t)(bm + wid * 32 + srw) * K) * 2 + sw;
  const char* Bb = (const char*)Bt + ((size_t)(bn + wid * 32 + srw) * K) * 2 + sw;
  f32x4 acc[4][4] = {};
  for (int k0 = 0; k0 < K; k0 += 64) {
    __syncthreads();   // WAR: all waves done reading previous tile
#pragma unroll
    for (int g = 0; g < 4; ++g) {
      gload16(Ab + (size_t)(g * 8) * K * 2 + (size_t)k0 * 2,
              (char*)&As[0][0] + (wid * 32 + g * 8) * 128);
      gload16(Bb + (size_t)(g * 8) * K * 2 + (size_t)k0 * 2,
              (char*)&Bs[0][0] + (wid * 32 + g * 8) * 128);
    }
    __syncthreads();   // RAW: barrier drains vmcnt -> staged data visible
    f16x8 af[4][2], bf[4][2];
#pragma unroll
    for (int i = 0; i < 4; ++i)
#pragma unroll
      for (int kk = 0; kk < 2; ++kk) {
        af[i][kk] = *reinterpret_cast<const f16x8*>(
            (const char*)&As[0][0] + (wm + i * 16 + rr) * 128 +
            ((kk * 64 + rg * 16) ^ ((rr & 7) << 4)));
        bf[i][kk] = *reinterpret_cast<const f16x8*>(
            (const char*)&Bs[0][0] + (wn + i * 16 + rr) * 128 +
            ((kk * 64 + rg * 16) ^ ((rr & 7) << 4)));
      }
#pragma unroll
    for (int kk = 0; kk < 2; ++kk)
#pragma unroll
      for (int i = 0; i < 4; ++i)
#pragma unroll
        for (int j = 0; j < 4; ++j)
          acc[i][j] = __builtin_amdgcn_mfma_f32_16x16x32_f16(af[i][kk], bf[j][kk],
                                                             acc[i][j], 0, 0, 0);
  }
#pragma unroll
  for (int i = 0; i < 4; ++i)
#pragma unroll
    for (int j = 0; j < 4; ++j)
#pragma unroll
      for (int r = 0; r < 4; ++r)
        C[(size_t)(bm + wm + i * 16 + rg * 4 + r) * N + (bn + wn + j * 16 + rr)] =
            (OT)acc[i][j][r];
}

// ---------------- RMSNorm + RoPE for K and V, f16 in / f16 out ----------------
// K is pre-scaled by LOG2E so QK^T logits are in log2 units.
__launch_bounds__(256, 4)
__global__ void norm_rope_kv(const f16* __restrict__ qkv, const float* __restrict__ cosb,
                             const float* __restrict__ sinb, const float* __restrict__ ksc,
                             f16* __restrict__ kf, f16* __restrict__ vb) {
  int gw = blockIdx.x * 4 + (threadIdx.x >> 6);
  int lane = threadIdx.x & 63;
  int row = gw >> 3, c = gw & 7;
  int b = row >> 11, s = row & (S_ - 1);
  int col = (c < 4) ? (2048 + c * 128) : (2560 + (c - 4) * 128);
  const f16* src = qkv + (size_t)row * NQKV_ + col;
  unsigned int u = *reinterpret_cast<const unsigned int*>(src + lane * 2);
  f16 p2[2]; __builtin_memcpy(p2, &u, 4);
  float vx = (float)p2[0], vy = (float)p2[1];
  float ss = vx * vx + vy * vy;
#pragma unroll
  for (int off = 32; off; off >>= 1) ss += __shfl_xor(ss, off);
  float inv = rsqrtf(ss * (1.0f / HD_) + EPS_);
  float x0 = vx * inv, x1 = vy * inv;
  int d0 = lane * 2;
  f16* dst;
  size_t idx;
  if (c < 4) {  // k: (1+scale) then rope on dims [0,64), then *LOG2E
    x0 *= (1.0f + ksc[d0]);
    x1 *= (1.0f + ksc[d0 + 1]);
    float y0 = __shfl_xor(x0, 16);
    float y1 = __shfl_xor(x1, 16);
    if (d0 < ROT_) {
      int dm = d0 & 31;
      float cs0 = cosb[s * 32 + dm],     sn0 = sinb[s * 32 + dm];
      float cs1 = cosb[s * 32 + dm + 1], sn1 = sinb[s * 32 + dm + 1];
      if (d0 < 32) { x0 = x0 * cs0 - y0 * sn0; x1 = x1 * cs1 - y1 * sn1; }
      else         { x0 = x0 * cs0 + y0 * sn0; x1 = x1 * cs1 + y1 * sn1; }
    }
    x0 *= LOG2E; x1 *= LOG2E;
    dst = kf; idx = ((size_t)((b * KVH_ + c) * S_ + s)) * HD_ + d0;
  } else {      // v: plain rmsnorm
    dst = vb; idx = ((size_t)((b * KVH_ + (c - 4)) * S_ + s)) * HD_ + d0;
  }
  f16 o[2] = { (f16)x0, (f16)x1 };
  unsigned int pk; __builtin_memcpy(&pk, o, 4);
  *reinterpret_cast<unsigned int*>(dst + idx) = pk;
}

// ---------------- flash attention v8b: swapped QK^T, in-register softmax ----------
// 512 blocks x 256 thr (4 waves x 32 q-rows). KVBLK=64 double-buffered staging via
// global_load_lds w16 (XOR swizzle ^((row&7)<<4)). Swapped 32x32 MFMA QK^T -> lane
// owns q=lane&31; in-lane softmax + one shfl_xor(32); P->B-frag via cvt_pkrtz +
// v_permlane32_swap_b32 (T12); PV = mfma(V^T-frag, P^T-frag). Defer-max, log2 domain.
// NOTE: needs launch_bounds(256,2) — acc uses 64 AGPR + ~108 VGPR (unified file);
// (256,4) caps at 128 and spills to scratch (round-13 regression: 65 -> 146 us).
__launch_bounds__(256, 2)
__global__ void flash_attn(const f16* __restrict__ qkv, const float* __restrict__ cosb,
                           const float* __restrict__ sinb, const float* __restrict__ qsc,
                           const f16* __restrict__ kfp, const f16* __restrict__ vt,
                           f16* __restrict__ ctxf) {
  __shared__ __attribute__((aligned(16))) f16 Ks[2][KVBLK][128];   // 32 KB
  __shared__ __attribute__((aligned(16))) f16 Vs[2][128][KVBLK];   // 32 KB
  const int id = blockIdx.x;
  const int g8 = id & 7, rest = id >> 3;          // rest in [0,64)
  const int b = g8 >> 2, kvh = g8 & 3;
  int hh, qtile;
  if (rest < 32) { hh = rest >> 3; qtile = 8 + (rest & 7); }     // heavy: 18 tiles
  else { int lv = rest - 32; hh = lv >> 3; qtile = lv & 7; }     // light: 2..16
  const int h = kvh * 4 + hh;
  const int lane = threadIdx.x & 63, w = threadIdx.x >> 6;
  const int ql = lane & 31;          // this lane's q column
  const int hi = lane >> 5;          // half (0/1)
  const int qBase = qtile * QBLK;
  const int qw = qBase + w * 32;
  const int q = qw + ql;             // sequence position
  const f16* Kh = kfp + (size_t)(b * KVH_ + kvh) * S_ * HD_;
  const f16* Vh = vt  + (size_t)(b * KVH_ + kvh) * HD_ * S_;

  // ---- q prep: lane loads 64 f16 of row q (d = kk*16 + hi*8 + j), rmsnorm,
  //      scale, rope (lane-local pairs kk<->kk+2), cvt to B-frag layout ----
  f16x8 qf[8];
  {
    const f16* qrow = qkv + (size_t)(b * S_ + q) * NQKV_ + h * HD_;
    float qv[8][8];
    float ssq = 0.f;
#pragma unroll
    for (int kk = 0; kk < 8; ++kk) {
      f16x8 u = *reinterpret_cast<const f16x8*>(qrow + kk * 16 + hi * 8);
#pragma unroll
      for (int j = 0; j < 8; ++j) {
        qv[kk][j] = (float)u[j];
        ssq += qv[kk][j] * qv[kk][j];
      }
    }
    ssq += __shfl_xor(ssq, 32);   // partner lane has the other 64 dims
    float inv = rsqrtf(ssq * (1.0f / HD_) + EPS_);
#pragma unroll
    for (int kk = 0; kk < 8; ++kk)
#pragma unroll
      for (int j = 0; j < 8; ++j)
        qv[kk][j] *= inv * (1.0f + qsc[kk * 16 + hi * 8 + j]);
    const float* cs = cosb + (size_t)q * 32;
    const float* sn = sinb + (size_t)q * 32;
#pragma unroll
    for (int kk = 0; kk < 2; ++kk)
#pragma unroll
      for (int j = 0; j < 8; ++j) {
        int d = kk * 16 + hi * 8 + j;          // in [0,32)
        float c = cs[d], s_ = sn[d];
        float x0 = qv[kk][j], x1 = qv[kk + 2][j];
        qv[kk][j]     = x0 * c - x1 * s_;
        qv[kk + 2][j] = x1 * c + x0 * s_;
      }
#pragma unroll
    for (int kk = 0; kk < 8; ++kk)
#pragma unroll
      for (int j = 0; j < 8; ++j)
        qf[kk][j] = (f16)qv[kk][j];
  }

  f32x16 acc[4] = {};
  float m_run = NINF, msafe = 0.f, l_run = 0.f;

  int kvStart = qBase - (WINDOW_ - 1);
  if (kvStart < 0) kvStart = 0;
  kvStart &= ~(KVBLK - 1);
  const int ntile = (qBase + QBLK - kvStart) >> 6;

  const int k_r0 = lane >> 4;          // 0..3
  const int k_cb = (lane & 15) * 16;
  const int v_r0 = lane >> 3;          // 0..7
  const int v_cb = (lane & 7) * 16;

#define STAGE(bufs, key0_)                                                           \
  do {                                                                               \
    _Pragma("unroll")                                                                \
    for (int gg = 0; gg < 4; ++gg) {                                                 \
      int krow = gg * 4 + k_r0;                                                      \
      gload16((const char*)Kh + (size_t)((key0_) + w * 16 + krow) * 256 +            \
                  (k_cb ^ ((krow & 7) << 4)),                                        \
              (char*)&Ks[bufs][0][0] + (w * 16 + gg * 4) * 256);                     \
      int vrow = gg * 8 + v_r0;                                                      \
      gload16((const char*)Vh + (size_t)(w * 32 + vrow) * (S_ * 2) +                 \
                  (size_t)(key0_) * 2 + (v_cb ^ ((vrow & 7) << 4)),                  \
              (char*)&Vs[bufs][0][0] + (w * 32 + gg * 8) * 128);                     \
    }                                                                                \
  } while (0)

  STAGE(0, kvStart);
  __syncthreads();

  for (int t = 0; t < ntile; ++t) {
    const int key0 = kvStart + t * KVBLK;
    const int buf = t & 1;
    if (t + 1 < ntile) STAGE(buf ^ 1, key0 + KVBLK);

    const bool live = (key0 <= qw + 31) && (key0 + 63 >= qw - (WINDOW_ - 1));
    if (live) {
      // ---- QK^T swapped: S^T[key][q], lane holds q=ql, keys via reg map ----
      f32x16 st[2];
#pragma unroll
      for (int kt = 0; kt < 2; ++kt) {
        const int rt = kt * 32 + ql;
        const char* kbase = (const char*)&Ks[buf][0][0] + rt * 256;
        const int swz = (rt & 7) << 4;
        f32x16 s = {};
#pragma unroll
        for (int kk = 0; kk < 8; ++kk) {
          f16x8 kfr = *reinterpret_cast<const f16x8*>(kbase + ((kk * 32 + hi * 16) ^ swz));
          s = __builtin_amdgcn_mfma_f32_32x32x16_f16(kfr, qf[kk], s, 0, 0, 0);
        }
        st[kt] = s;
      }

      // ---- mask (skipped for interior tiles); key = key0+kt*32+(r&3)+8(r>>2)+4hi ----
      const bool interior = (key0 + 63 <= qw) && (key0 >= qw - 992);
      if (!interior) {
#pragma unroll
        for (int kt = 0; kt < 2; ++kt)
#pragma unroll
          for (int r = 0; r < 16; ++r) {
            int kj = key0 + kt * 32 + ((r & 3) + 8 * (r >> 2) + 4 * hi);
            bool valid = (kj <= q) && (q - kj < WINDOW_);
            if (!valid) st[kt][r] = NINF;
          }
      }

      // ---- in-lane row max + one cross-half swap ----
      float tm = st[0][0];
#pragma unroll
      for (int r = 1; r < 16; ++r) tm = fmaxf(tm, st[0][r]);
#pragma unroll
      for (int r = 0; r < 16; ++r) tm = fmaxf(tm, st[1][r]);
      tm = fmaxf(tm, __shfl_xor(tm, 32));

      // ---- defer-max rescale ----
      bool defer = (tm - m_run <= DEFER_THR);
      if (!__all(defer)) {
        float mn = fmaxf(m_run, tm);
        float alpha = (m_run == NINF) ? 0.f : EXP2F(m_run - mn);
        m_run = mn;
        msafe = (mn == NINF) ? 0.f : mn;
#pragma unroll
        for (int dt = 0; dt < 4; ++dt)
#pragma unroll
          for (int r = 0; r < 16; ++r) acc[dt][r] *= alpha;
        l_run *= alpha;
      }
      // ---- exp (log2 domain) + row-sum ----
      float ps = 0.f;
#pragma unroll
      for (int kt = 0; kt < 2; ++kt)
#pragma unroll
        for (int r = 0; r < 16; ++r) {
          float p = EXP2F(st[kt][r] - msafe);
          st[kt][r] = p;
          ps += p;
        }
      ps += __shfl_xor(ps, 32);
      l_run += ps;

      // ---- P -> B-fragments in-register (cvt_pk + permlane32_swap) ----
      f16x8 pf[4];
#pragma unroll
      for (int ks = 0; ks < 4; ++ks) {
        const int kt = ks >> 1, rb = (ks & 1) * 8;
        int w0 = cvtpk_i(st[kt][rb + 0], st[kt][rb + 1]);
        int w2 = cvtpk_i(st[kt][rb + 4], st[kt][rb + 5]);
        asm volatile("v_permlane32_swap_b32 %0, %1" : "+v"(w0), "+v"(w2));
        int w1 = cvtpk_i(st[kt][rb + 2], st[kt][rb + 3]);
        int w3 = cvtpk_i(st[kt][rb + 6], st[kt][rb + 7]);
        asm volatile("v_permlane32_swap_b32 %0, %1" : "+v"(w1), "+v"(w3));
        int wi[4] = { w0, w1, w2, w3 };
        __builtin_memcpy(&pf[ks], wi, 16);
      }

      // ---- PV swapped: ctx^T[d][q] += V^T-frag x P^T-frag ----
      __builtin_amdgcn_s_setprio(1);
#pragma unroll
      for (int dt = 0; dt < 4; ++dt) {
        const int d = dt * 32 + ql;
        const char* vbase = (const char*)&Vs[buf][0][0] + d * 128;
        const int swz = (d & 7) << 4;
#pragma unroll
        for (int ks = 0; ks < 4; ++ks) {
          f16x8 vf = *reinterpret_cast<const f16x8*>(vbase + ((ks * 32 + hi * 16) ^ swz));
          acc[dt] = __builtin_amdgcn_mfma_f32_32x32x16_f16(vf, pf[ks], acc[dt], 0, 0, 0);
        }
      }
      __builtin_amdgcn_s_setprio(0);
    }

    __syncthreads();   // drains prefetch vmcnt + all waves done with buf
  }
#undef STAGE

  // ---- epilogue: lane owns q; d = dt*32 + 8*g + 4*hi + r -> 8B packed stores ----
  const float rinv = 1.0f / l_run;
  f16* orow = ctxf + (size_t)(b * S_ + q) * D_ + h * HD_;
#pragma unroll
  for (int dt = 0; dt < 4; ++dt)
#pragma unroll
    for (int g = 0; g < 4; ++g) {
      f16x4 o;
#pragma unroll
      for (int r = 0; r < 4; ++r) o[r] = (f16)(acc[dt][g * 4 + r] * rinv);
      *reinterpret_cast<f16x4*>(orow + dt * 32 + 8 * g + 4 * hi) = o;
    }
}

extern "C" void kernel_launch(void* const* d_in, const int* in_sizes, int n_in,
                              void* d_out, int out_size, void* d_ws, size_t ws_size,
                              hipStream_t stream) {
  const float* x    = (const float*)d_in[0];
  // d_in[1] = mask (recomputed analytically)
  const float* cosb = (const float*)d_in[2];
  const float* sinb = (const float*)d_in[3];
  const float* Wq   = (const float*)d_in[4];
  const float* Wk   = (const float*)d_in[5];
  const float* Wv   = (const float*)d_in[6];
  const float* Wo   = (const float*)d_in[7];
  const float* qsc  = (const float*)d_in[8];
  const float* ksc  = (const float*)d_in[9];
  float* out = (float*)d_out;

  char* ws = (char*)d_ws;
  const size_t MB = 1ull << 20;
  // [0,16)  xh fp16         -> after gemm0 reused: ctxf fp16
  // [16,28) wqkvT fp16      -> after gemm0 reused: kf[16,20) vb[20,24) vtb[24,28)
  // [28,36) woT fp16
  // [36,60) qkv fp16
  f16* xh    = (f16*)(ws + 0 * MB);
  f16* ctxf  = (f16*)(ws + 0 * MB);
  f16* wqkvT = (f16*)(ws + 16 * MB);
  f16* kf    = (f16*)(ws + 16 * MB);
  f16* vb    = (f16*)(ws + 20 * MB);
  f16* vtb   = (f16*)(ws + 24 * MB);
  f16* woT   = (f16*)(ws + 28 * MB);
  f16* qkvh  = (f16*)(ws + 36 * MB);

  cast_f32_f16<<<dim3(M_ * D_ / 8 / 256), 256, 0, stream>>>(x, xh, M_ * D_ / 8);
  transpose_f32_f16<<<dim3(64, 64), 256, 0, stream>>>(Wq, wqkvT, D_, 2048);
  transpose_f32_f16<<<dim3(16, 64), 256, 0, stream>>>(Wk, wqkvT + (size_t)2048 * D_, D_, 512);
  transpose_f32_f16<<<dim3(16, 64), 256, 0, stream>>>(Wv, wqkvT + (size_t)2560 * D_, D_, 512);
  transpose_f32_f16<<<dim3(64, 64), 256, 0, stream>>>(Wo, woT, D_, D_);
  gemm_f16<f16><<<dim3(NQKV_ / 128, M_ / 128), 256, 0, stream>>>(
      xh, wqkvT, qkvh, M_, NQKV_, D_);
  norm_rope_kv<<<dim3(M_ * 8 / 4), 256, 0, stream>>>(qkvh, cosb, sinb, ksc, kf, vb);
  transpose16<<<dim3(HD_ / 32, S_ / 32, B_ * KVH_), 256, 0, stream>>>(
      (const ushort_t*)vb, (ushort_t*)vtb, S_, HD_);
  flash_attn<<<dim3((S_ / QBLK) * H_ * B_), 256, 0, stream>>>(
      qkvh, cosb, sinb, qsc, kf, vtb, ctxf);
  gemm_f16<float><<<dim3(D_ / 128, M_ / 128), 256, 0, stream>>>(
      ctxf, woT, out, M_, D_, D_);
}

// Round 15
// 197.941 us; speedup vs baseline: 1.4050x; 1.0245x over previous
//
#include <hip/hip_runtime.h>
#include <stdint.h>

#define B_ 2
#define S_ 2048
#define D_ 2048
#define H_ 16
#define KVH_ 4
#define HD_ 128
#define ROT_ 64
#define WINDOW_ 1024
#define EPS_ 1e-6f
#define M_ (B_ * S_)
#define NQKV_ 3072

#define QBLK 128
#define KVBLK 64
#define LOG2E 1.44269504088896340736f
#define DEFER_THR 8.0f

typedef unsigned short ushort_t;
typedef _Float16 f16;
typedef float f32x4 __attribute__((ext_vector_type(4)));
typedef float f32x16 __attribute__((ext_vector_type(16)));
typedef f16 f16x4 __attribute__((ext_vector_type(4)));
typedef f16 f16x8 __attribute__((ext_vector_type(8)));

#define NINF (-__builtin_inff())
#define EXP2F(x) __builtin_exp2f(x)

// async global->LDS, 16B per lane. dst must be wave-uniform; HW adds lane*16.
__device__ __forceinline__ void gload16(const void* g, void* l) {
  __builtin_amdgcn_global_load_lds(
      (const __attribute__((address_space(1))) void*)g,
      (__attribute__((address_space(3))) void*)l, 16, 0, 0);
}

// pack 2 f32 -> 1 u32 of 2 fp16 (rtz)
__device__ __forceinline__ int cvtpk_i(float a, float b) {
  auto h = __builtin_amdgcn_cvt_pkrtz(a, b);
  int r; __builtin_memcpy(&r, &h, 4); return r;
}

// ---------------- fused prep: x cast (f32->f16) + 4 weight transposes ----------
// grid 14336 x 256: [0,4096) cast x; [4096,8192) Wq^T; [8192,9216) Wk^T;
// [9216,10240) Wv^T; [10240,14336) Wo^T. One launch replaces 5.
__launch_bounds__(256, 4)
__global__ void prep(const float* __restrict__ x, f16* __restrict__ xh,
                     const float* __restrict__ Wq, const float* __restrict__ Wk,
                     const float* __restrict__ Wv, const float* __restrict__ Wo,
                     f16* __restrict__ wqkvT, f16* __restrict__ woT) {
  __shared__ float tile[32][33];
  int id = blockIdx.x;
  if (id < 4096) {   // cast path: 8 f32 -> 8 f16 per thread
    int i = id * 256 + threadIdx.x;
    float4 a = reinterpret_cast<const float4*>(x)[i * 2];
    float4 b = reinterpret_cast<const float4*>(x)[i * 2 + 1];
    f16x8 o = { (f16)a.x, (f16)a.y, (f16)a.z, (f16)a.w,
                (f16)b.x, (f16)b.y, (f16)b.z, (f16)b.w };
    reinterpret_cast<f16x8*>(xh)[i] = o;
    return;
  }
  id -= 4096;
  const float* src; f16* dst; int C, bx, by;
  if (id < 4096)      { src = Wq; dst = wqkvT;                      C = 2048; bx = id & 63; by = id >> 6; }
  else if (id < 5120) { id -= 4096; src = Wk; dst = wqkvT + (size_t)2048 * D_; C = 512; bx = id & 15; by = id >> 4; }
  else if (id < 6144) { id -= 5120; src = Wv; dst = wqkvT + (size_t)2560 * D_; C = 512; bx = id & 15; by = id >> 4; }
  else                { id -= 6144; src = Wo; dst = woT;            C = 2048; bx = id & 63; by = id >> 6; }
  const int c0 = bx * 32, r0 = by * 32;
  const int tx = threadIdx.x & 31, ty = threadIdx.x >> 5;
#pragma unroll
  for (int i = 0; i < 32; i += 8)
    tile[ty + i][tx] = src[(size_t)(r0 + ty + i) * C + c0 + tx];
  __syncthreads();
#pragma unroll
  for (int i = 0; i < 32; i += 8)
    dst[(size_t)(c0 + ty + i) * D_ + r0 + tx] = (f16)tile[tx][ty + i];
}

// ---------------- batched transpose 16-bit [R][C] -> [C][R] ----------------
__launch_bounds__(256, 4)
__global__ void transpose16(const ushort_t* __restrict__ src, ushort_t* __restrict__ dst,
                            int R, int C) {
  __shared__ ushort_t tile[32][33];
  size_t base = (size_t)blockIdx.z * R * C;
  src += base; dst += base;
  int c0 = blockIdx.x * 32, r0 = blockIdx.y * 32;
  int tx = threadIdx.x & 31, ty = threadIdx.x >> 5;
#pragma unroll
  for (int i = 0; i < 32; i += 8)
    tile[ty + i][tx] = src[(size_t)(r0 + ty + i) * C + c0 + tx];
  __syncthreads();
#pragma unroll
  for (int i = 0; i < 32; i += 8)
    dst[(size_t)(c0 + ty + i) * R + r0 + tx] = tile[tx][ty + i];
}

// ---------------- fp16 GEMM: single-buffered m97 structure, templated output ----
template<typename OT>
__launch_bounds__(256, 2)
__global__ void gemm_f16(const f16* __restrict__ A, const f16* __restrict__ Bt,
                         OT* __restrict__ C, int M, int N, int K) {
  __shared__ __attribute__((aligned(16))) f16 As[128][64];
  __shared__ __attribute__((aligned(16))) f16 Bs[128][64];
  const int gx = gridDim.x;
  const int nwg = gx * gridDim.y;
  const int flat = blockIdx.y * gx + blockIdx.x;
  const int q8 = nwg >> 3;
  const int id2 = (flat & 7) * q8 + (flat >> 3);
  const int bm = (id2 / gx) * 128, bn = (id2 % gx) * 128;
  const int tid = threadIdx.x;
  const int lane = tid & 63, wid = tid >> 6;
  const int wm = (wid >> 1) * 64, wn = (wid & 1) * 64;
  const int rr = lane & 15, rg = lane >> 4;
  const int sw = (((lane & 7) ^ (lane >> 3)) << 4);
  const int srw = lane >> 3;
  const char* Ab = (const char*)A + ((size_t)(bm + wid * 32 + srw) * K) * 2 + sw;
  const char* Bb = (const char*)Bt + ((size_t)(bn + wid * 32 + srw) * K) * 2 + sw;
  f32x4 acc[4][4] = {};
  for (int k0 = 0; k0 < K; k0 += 64) {
    __syncthreads();   // WAR: all waves done reading previous tile
#pragma unroll
    for (int g = 0; g < 4; ++g) {
      gload16(Ab + (size_t)(g * 8) * K * 2 + (size_t)k0 * 2,
              (char*)&As[0][0] + (wid * 32 + g * 8) * 128);
      gload16(Bb + (size_t)(g * 8) * K * 2 + (size_t)k0 * 2,
              (char*)&Bs[0][0] + (wid * 32 + g * 8) * 128);
    }
    __syncthreads();   // RAW: barrier drains vmcnt -> staged data visible
    f16x8 af[4][2], bf[4][2];
#pragma unroll
    for (int i = 0; i < 4; ++i)
#pragma unroll
      for (int kk = 0; kk < 2; ++kk) {
        af[i][kk] = *reinterpret_cast<const f16x8*>(
            (const char*)&As[0][0] + (wm + i * 16 + rr) * 128 +
            ((kk * 64 + rg * 16) ^ ((rr & 7) << 4)));
        bf[i][kk] = *reinterpret_cast<const f16x8*>(
            (const char*)&Bs[0][0] + (wn + i * 16 + rr) * 128 +
            ((kk * 64 + rg * 16) ^ ((rr & 7) << 4)));
      }
#pragma unroll
    for (int kk = 0; kk < 2; ++kk)
#pragma unroll
      for (int i = 0; i < 4; ++i)
#pragma unroll
        for (int j = 0; j < 4; ++j)
          acc[i][j] = __builtin_amdgcn_mfma_f32_16x16x32_f16(af[i][kk], bf[j][kk],
                                                             acc[i][j], 0, 0, 0);
  }
#pragma unroll
  for (int i = 0; i < 4; ++i)
#pragma unroll
    for (int j = 0; j < 4; ++j)
#pragma unroll
      for (int r = 0; r < 4; ++r)
        C[(size_t)(bm + wm + i * 16 + rg * 4 + r) * N + (bn + wn + j * 16 + rr)] =
            (OT)acc[i][j][r];
}

// ---------------- RMSNorm + RoPE for K and V, f16 in / f16 out ----------------
// K is pre-scaled by LOG2E so QK^T logits are in log2 units.
__launch_bounds__(256, 4)
__global__ void norm_rope_kv(const f16* __restrict__ qkv, const float* __restrict__ cosb,
                             const float* __restrict__ sinb, const float* __restrict__ ksc,
                             f16* __restrict__ kf, f16* __restrict__ vb) {
  int gw = blockIdx.x * 4 + (threadIdx.x >> 6);
  int lane = threadIdx.x & 63;
  int row = gw >> 3, c = gw & 7;
  int b = row >> 11, s = row & (S_ - 1);
  int col = (c < 4) ? (2048 + c * 128) : (2560 + (c - 4) * 128);
  const f16* src = qkv + (size_t)row * NQKV_ + col;
  unsigned int u = *reinterpret_cast<const unsigned int*>(src + lane * 2);
  f16 p2[2]; __builtin_memcpy(p2, &u, 4);
  float vx = (float)p2[0], vy = (float)p2[1];
  float ss = vx * vx + vy * vy;
#pragma unroll
  for (int off = 32; off; off >>= 1) ss += __shfl_xor(ss, off);
  float inv = rsqrtf(ss * (1.0f / HD_) + EPS_);
  float x0 = vx * inv, x1 = vy * inv;
  int d0 = lane * 2;
  f16* dst;
  size_t idx;
  if (c < 4) {  // k: (1+scale) then rope on dims [0,64), then *LOG2E
    x0 *= (1.0f + ksc[d0]);
    x1 *= (1.0f + ksc[d0 + 1]);
    float y0 = __shfl_xor(x0, 16);
    float y1 = __shfl_xor(x1, 16);
    if (d0 < ROT_) {
      int dm = d0 & 31;
      float cs0 = cosb[s * 32 + dm],     sn0 = sinb[s * 32 + dm];
      float cs1 = cosb[s * 32 + dm + 1], sn1 = sinb[s * 32 + dm + 1];
      if (d0 < 32) { x0 = x0 * cs0 - y0 * sn0; x1 = x1 * cs1 - y1 * sn1; }
      else         { x0 = x0 * cs0 + y0 * sn0; x1 = x1 * cs1 + y1 * sn1; }
    }
    x0 *= LOG2E; x1 *= LOG2E;
    dst = kf; idx = ((size_t)((b * KVH_ + c) * S_ + s)) * HD_ + d0;
  } else {      // v: plain rmsnorm
    dst = vb; idx = ((size_t)((b * KVH_ + (c - 4)) * S_ + s)) * HD_ + d0;
  }
  f16 o[2] = { (f16)x0, (f16)x1 };
  unsigned int pk; __builtin_memcpy(&pk, o, 4);
  *reinterpret_cast<unsigned int*>(dst + idx) = pk;
}

// ---------------- flash attention v8b: swapped QK^T, in-register softmax ----------
// 512 blocks x 256 thr (4 waves x 32 q-rows). KVBLK=64 double-buffered staging via
// global_load_lds w16 (XOR swizzle ^((row&7)<<4)). Swapped 32x32 MFMA QK^T -> lane
// owns q=lane&31; in-lane softmax + one shfl_xor(32); P->B-frag via cvt_pkrtz +
// v_permlane32_swap_b32 (T12); PV = mfma(V^T-frag, P^T-frag). Defer-max, log2 domain.
// NOTE: needs launch_bounds(256,2) — acc uses 64 AGPR + ~108 VGPR (unified file);
// (256,4) caps at 128 and spills to scratch (round-13 regression: 65 -> 146 us).
__launch_bounds__(256, 2)
__global__ void flash_attn(const f16* __restrict__ qkv, const float* __restrict__ cosb,
                           const float* __restrict__ sinb, const float* __restrict__ qsc,
                           const f16* __restrict__ kfp, const f16* __restrict__ vt,
                           f16* __restrict__ ctxf) {
  __shared__ __attribute__((aligned(16))) f16 Ks[2][KVBLK][128];   // 32 KB
  __shared__ __attribute__((aligned(16))) f16 Vs[2][128][KVBLK];   // 32 KB
  const int id = blockIdx.x;
  const int g8 = id & 7, rest = id >> 3;          // rest in [0,64)
  const int b = g8 >> 2, kvh = g8 & 3;
  int hh, qtile;
  if (rest < 32) { hh = rest >> 3; qtile = 8 + (rest & 7); }     // heavy: 18 tiles
  else { int lv = rest - 32; hh = lv >> 3; qtile = lv & 7; }     // light: 2..16
  const int h = kvh * 4 + hh;
  const int lane = threadIdx.x & 63, w = threadIdx.x >> 6;
  const int ql = lane & 31;          // this lane's q column
  const int hi = lane >> 5;          // half (0/1)
  const int qBase = qtile * QBLK;
  const int qw = qBase + w * 32;
  const int q = qw + ql;             // sequence position
  const f16* Kh = kfp + (size_t)(b * KVH_ + kvh) * S_ * HD_;
  const f16* Vh = vt  + (size_t)(b * KVH_ + kvh) * HD_ * S_;

  // ---- q prep: lane loads 64 f16 of row q (d = kk*16 + hi*8 + j), rmsnorm,
  //      scale, rope (lane-local pairs kk<->kk+2), cvt to B-frag layout ----
  f16x8 qf[8];
  {
    const f16* qrow = qkv + (size_t)(b * S_ + q) * NQKV_ + h * HD_;
    float qv[8][8];
    float ssq = 0.f;
#pragma unroll
    for (int kk = 0; kk < 8; ++kk) {
      f16x8 u = *reinterpret_cast<const f16x8*>(qrow + kk * 16 + hi * 8);
#pragma unroll
      for (int j = 0; j < 8; ++j) {
        qv[kk][j] = (float)u[j];
        ssq += qv[kk][j] * qv[kk][j];
      }
    }
    ssq += __shfl_xor(ssq, 32);   // partner lane has the other 64 dims
    float inv = rsqrtf(ssq * (1.0f / HD_) + EPS_);
#pragma unroll
    for (int kk = 0; kk < 8; ++kk)
#pragma unroll
      for (int j = 0; j < 8; ++j)
        qv[kk][j] *= inv * (1.0f + qsc[kk * 16 + hi * 8 + j]);
    const float* cs = cosb + (size_t)q * 32;
    const float* sn = sinb + (size_t)q * 32;
#pragma unroll
    for (int kk = 0; kk < 2; ++kk)
#pragma unroll
      for (int j = 0; j < 8; ++j) {
        int d = kk * 16 + hi * 8 + j;          // in [0,32)
        float c = cs[d], s_ = sn[d];
        float x0 = qv[kk][j], x1 = qv[kk + 2][j];
        qv[kk][j]     = x0 * c - x1 * s_;
        qv[kk + 2][j] = x1 * c + x0 * s_;
      }
#pragma unroll
    for (int kk = 0; kk < 8; ++kk)
#pragma unroll
      for (int j = 0; j < 8; ++j)
        qf[kk][j] = (f16)qv[kk][j];
  }

  f32x16 acc[4] = {};
  float m_run = NINF, msafe = 0.f, l_run = 0.f;

  int kvStart = qBase - (WINDOW_ - 1);
  if (kvStart < 0) kvStart = 0;
  kvStart &= ~(KVBLK - 1);
  const int ntile = (qBase + QBLK - kvStart) >> 6;

  const int k_r0 = lane >> 4;          // 0..3
  const int k_cb = (lane & 15) * 16;
  const int v_r0 = lane >> 3;          // 0..7
  const int v_cb = (lane & 7) * 16;

#define STAGE(bufs, key0_)                                                           \
  do {                                                                               \
    _Pragma("unroll")                                                                \
    for (int gg = 0; gg < 4; ++gg) {                                                 \
      int krow = gg * 4 + k_r0;                                                      \
      gload16((const char*)Kh + (size_t)((key0_) + w * 16 + krow) * 256 +            \
                  (k_cb ^ ((krow & 7) << 4)),                                        \
              (char*)&Ks[bufs][0][0] + (w * 16 + gg * 4) * 256);                     \
      int vrow = gg * 8 + v_r0;                                                      \
      gload16((const char*)Vh + (size_t)(w * 32 + vrow) * (S_ * 2) +                 \
                  (size_t)(key0_) * 2 + (v_cb ^ ((vrow & 7) << 4)),                  \
              (char*)&Vs[bufs][0][0] + (w * 32 + gg * 8) * 128);                     \
    }                                                                                \
  } while (0)

  STAGE(0, kvStart);
  __syncthreads();

  for (int t = 0; t < ntile; ++t) {
    const int key0 = kvStart + t * KVBLK;
    const int buf = t & 1;
    if (t + 1 < ntile) STAGE(buf ^ 1, key0 + KVBLK);

    const bool live = (key0 <= qw + 31) && (key0 + 63 >= qw - (WINDOW_ - 1));
    if (live) {
      // ---- QK^T swapped: S^T[key][q], lane holds q=ql, keys via reg map ----
      f32x16 st[2];
#pragma unroll
      for (int kt = 0; kt < 2; ++kt) {
        const int rt = kt * 32 + ql;
        const char* kbase = (const char*)&Ks[buf][0][0] + rt * 256;
        const int swz = (rt & 7) << 4;
        f32x16 s = {};
#pragma unroll
        for (int kk = 0; kk < 8; ++kk) {
          f16x8 kfr = *reinterpret_cast<const f16x8*>(kbase + ((kk * 32 + hi * 16) ^ swz));
          s = __builtin_amdgcn_mfma_f32_32x32x16_f16(kfr, qf[kk], s, 0, 0, 0);
        }
        st[kt] = s;
      }

      // ---- mask (skipped for interior tiles); key = key0+kt*32+(r&3)+8(r>>2)+4hi ----
      const bool interior = (key0 + 63 <= qw) && (key0 >= qw - 992);
      if (!interior) {
#pragma unroll
        for (int kt = 0; kt < 2; ++kt)
#pragma unroll
          for (int r = 0; r < 16; ++r) {
            int kj = key0 + kt * 32 + ((r & 3) + 8 * (r >> 2) + 4 * hi);
            bool valid = (kj <= q) && (q - kj < WINDOW_);
            if (!valid) st[kt][r] = NINF;
          }
      }

      // ---- in-lane row max + one cross-half swap ----
      float tm = st[0][0];
#pragma unroll
      for (int r = 1; r < 16; ++r) tm = fmaxf(tm, st[0][r]);
#pragma unroll
      for (int r = 0; r < 16; ++r) tm = fmaxf(tm, st[1][r]);
      tm = fmaxf(tm, __shfl_xor(tm, 32));

      // ---- defer-max rescale ----
      bool defer = (tm - m_run <= DEFER_THR);
      if (!__all(defer)) {
        float mn = fmaxf(m_run, tm);
        float alpha = (m_run == NINF) ? 0.f : EXP2F(m_run - mn);
        m_run = mn;
        msafe = (mn == NINF) ? 0.f : mn;
#pragma unroll
        for (int dt = 0; dt < 4; ++dt)
#pragma unroll
          for (int r = 0; r < 16; ++r) acc[dt][r] *= alpha;
        l_run *= alpha;
      }
      // ---- exp (log2 domain) + row-sum ----
      float ps = 0.f;
#pragma unroll
      for (int kt = 0; kt < 2; ++kt)
#pragma unroll
        for (int r = 0; r < 16; ++r) {
          float p = EXP2F(st[kt][r] - msafe);
          st[kt][r] = p;
          ps += p;
        }
      ps += __shfl_xor(ps, 32);
      l_run += ps;

      // ---- P -> B-fragments in-register (cvt_pk + permlane32_swap) ----
      f16x8 pf[4];
#pragma unroll
      for (int ks = 0; ks < 4; ++ks) {
        const int kt = ks >> 1, rb = (ks & 1) * 8;
        int w0 = cvtpk_i(st[kt][rb + 0], st[kt][rb + 1]);
        int w2 = cvtpk_i(st[kt][rb + 4], st[kt][rb + 5]);
        asm volatile("v_permlane32_swap_b32 %0, %1" : "+v"(w0), "+v"(w2));
        int w1 = cvtpk_i(st[kt][rb + 2], st[kt][rb + 3]);
        int w3 = cvtpk_i(st[kt][rb + 6], st[kt][rb + 7]);
        asm volatile("v_permlane32_swap_b32 %0, %1" : "+v"(w1), "+v"(w3));
        int wi[4] = { w0, w1, w2, w3 };
        __builtin_memcpy(&pf[ks], wi, 16);
      }

      // ---- PV swapped: ctx^T[d][q] += V^T-frag x P^T-frag ----
      __builtin_amdgcn_s_setprio(1);
#pragma unroll
      for (int dt = 0; dt < 4; ++dt) {
        const int d = dt * 32 + ql;
        const char* vbase = (const char*)&Vs[buf][0][0] + d * 128;
        const int swz = (d & 7) << 4;
#pragma unroll
        for (int ks = 0; ks < 4; ++ks) {
          f16x8 vf = *reinterpret_cast<const f16x8*>(vbase + ((ks * 32 + hi * 16) ^ swz));
          acc[dt] = __builtin_amdgcn_mfma_f32_32x32x16_f16(vf, pf[ks], acc[dt], 0, 0, 0);
        }
      }
      __builtin_amdgcn_s_setprio(0);
    }

    __syncthreads();   // drains prefetch vmcnt + all waves done with buf
  }
#undef STAGE

  // ---- epilogue: lane owns q; d = dt*32 + 8*g + 4*hi + r -> 8B packed stores ----
  const float rinv = 1.0f / l_run;
  f16* orow = ctxf + (size_t)(b * S_ + q) * D_ + h * HD_;
#pragma unroll
  for (int dt = 0; dt < 4; ++dt)
#pragma unroll
    for (int g = 0; g < 4; ++g) {
      f16x4 o;
#pragma unroll
      for (int r = 0; r < 4; ++r) o[r] = (f16)(acc[dt][g * 4 + r] * rinv);
      *reinterpret_cast<f16x4*>(orow + dt * 32 + 8 * g + 4 * hi) = o;
    }
}

extern "C" void kernel_launch(void* const* d_in, const int* in_sizes, int n_in,
                              void* d_out, int out_size, void* d_ws, size_t ws_size,
                              hipStream_t stream) {
  const float* x    = (const float*)d_in[0];
  // d_in[1] = mask (recomputed analytically)
  const float* cosb = (const float*)d_in[2];
  const float* sinb = (const float*)d_in[3];
  const float* Wq   = (const float*)d_in[4];
  const float* Wk   = (const float*)d_in[5];
  const float* Wv   = (const float*)d_in[6];
  const float* Wo   = (const float*)d_in[7];
  const float* qsc  = (const float*)d_in[8];
  const float* ksc  = (const float*)d_in[9];
  float* out = (float*)d_out;

  char* ws = (char*)d_ws;
  const size_t MB = 1ull << 20;
  // [0,16)  xh fp16         -> after gemm0 reused: ctxf fp16
  // [16,28) wqkvT fp16      -> after gemm0 reused: kf[16,20) vb[20,24) vtb[24,28)
  // [28,36) woT fp16
  // [36,60) qkv fp16
  f16* xh    = (f16*)(ws + 0 * MB);
  f16* ctxf  = (f16*)(ws + 0 * MB);
  f16* wqkvT = (f16*)(ws + 16 * MB);
  f16* kf    = (f16*)(ws + 16 * MB);
  f16* vb    = (f16*)(ws + 20 * MB);
  f16* vtb   = (f16*)(ws + 24 * MB);
  f16* woT   = (f16*)(ws + 28 * MB);
  f16* qkvh  = (f16*)(ws + 36 * MB);

  prep<<<dim3(14336), 256, 0, stream>>>(x, xh, Wq, Wk, Wv, Wo, wqkvT, woT);
  gemm_f16<f16><<<dim3(NQKV_ / 128, M_ / 128), 256, 0, stream>>>(
      xh, wqkvT, qkvh, M_, NQKV_, D_);
  norm_rope_kv<<<dim3(M_ * 8 / 4), 256, 0, stream>>>(qkvh, cosb, sinb, ksc, kf, vb);
  transpose16<<<dim3(HD_ / 32, S_ / 32, B_ * KVH_), 256, 0, stream>>>(
      (const ushort_t*)vb, (ushort_t*)vtb, S_, HD_);
  flash_attn<<<dim3((S_ / QBLK) * H_ * B_), 256, 0, stream>>>(
      qkvh, cosb, sinb, qsc, kf, vtb, ctxf);
  gemm_f16<float><<<dim3(D_ / 128, M_ / 128), 256, 0, stream>>>(
      ctxf, woT, out, M_, D_, D_);
}

// Round 17
// 194.819 us; speedup vs baseline: 1.4275x; 1.0160x over previous
//
#include <hip/hip_runtime.h>
#include <stdint.h>

#define B_ 2
#define S_ 2048
#define D_ 2048
#define H_ 16
#define KVH_ 4
#define HD_ 128
#define ROT_ 64
#define WINDOW_ 1024
#define EPS_ 1e-6f
#define M_ (B_ * S_)
#define NQKV_ 3072

#define QBLK 128
#define KVBLK 64
#define LOG2E 1.44269504088896340736f
#define DEFER_THR 8.0f

typedef unsigned short ushort_t;
typedef _Float16 f16;
typedef float f32x4 __attribute__((ext_vector_type(4)));
typedef float f32x16 __attribute__((ext_vector_type(16)));
typedef f16 f16x4 __attribute__((ext_vector_type(4)));
typedef f16 f16x8 __attribute__((ext_vector_type(8)));

#define NINF (-__builtin_inff())
#define EXP2F(x) __builtin_exp2f(x)

// async global->LDS, 16B per lane. dst must be wave-uniform; HW adds lane*16.
__device__ __forceinline__ void gload16(const void* g, void* l) {
  __builtin_amdgcn_global_load_lds(
      (const __attribute__((address_space(1))) void*)g,
      (__attribute__((address_space(3))) void*)l, 16, 0, 0);
}

// pack 2 f32 -> 1 u32 of 2 fp16 (rtz)
__device__ __forceinline__ int cvtpk_i(float a, float b) {
  auto h = __builtin_amdgcn_cvt_pkrtz(a, b);
  int r; __builtin_memcpy(&r, &h, 4); return r;
}

// ---------------- fused prep: x cast (f32->f16) + 4 weight transposes ----------
// grid 14336 x 256: [0,4096) cast x; [4096,8192) Wq^T; [8192,9216) Wk^T;
// [9216,10240) Wv^T; [10240,14336) Wo^T. One launch replaces 5.
__launch_bounds__(256, 4)
__global__ void prep(const float* __restrict__ x, f16* __restrict__ xh,
                     const float* __restrict__ Wq, const float* __restrict__ Wk,
                     const float* __restrict__ Wv, const float* __restrict__ Wo,
                     f16* __restrict__ wqkvT, f16* __restrict__ woT) {
  __shared__ float tile[32][33];
  int id = blockIdx.x;
  if (id < 4096) {   // cast path: 8 f32 -> 8 f16 per thread
    int i = id * 256 + threadIdx.x;
    float4 a = reinterpret_cast<const float4*>(x)[i * 2];
    float4 b = reinterpret_cast<const float4*>(x)[i * 2 + 1];
    f16x8 o = { (f16)a.x, (f16)a.y, (f16)a.z, (f16)a.w,
                (f16)b.x, (f16)b.y, (f16)b.z, (f16)b.w };
    reinterpret_cast<f16x8*>(xh)[i] = o;
    return;
  }
  id -= 4096;
  const float* src; f16* dst; int C, bx, by;
  if (id < 4096)      { src = Wq; dst = wqkvT;                      C = 2048; bx = id & 63; by = id >> 6; }
  else if (id < 5120) { id -= 4096; src = Wk; dst = wqkvT + (size_t)2048 * D_; C = 512; bx = id & 15; by = id >> 4; }
  else if (id < 6144) { id -= 5120; src = Wv; dst = wqkvT + (size_t)2560 * D_; C = 512; bx = id & 15; by = id >> 4; }
  else                { id -= 6144; src = Wo; dst = woT;            C = 2048; bx = id & 63; by = id >> 6; }
  const int c0 = bx * 32, r0 = by * 32;
  const int tx = threadIdx.x & 31, ty = threadIdx.x >> 5;
#pragma unroll
  for (int i = 0; i < 32; i += 8)
    tile[ty + i][tx] = src[(size_t)(r0 + ty + i) * C + c0 + tx];
  __syncthreads();
#pragma unroll
  for (int i = 0; i < 32; i += 8)
    dst[(size_t)(c0 + ty + i) * D_ + r0 + tx] = (f16)tile[tx][ty + i];
}

// ---------------- fp16 GEMM: single-buffered m97 structure, templated output ----
template<typename OT>
__launch_bounds__(256, 2)
__global__ void gemm_f16(const f16* __restrict__ A, const f16* __restrict__ Bt,
                         OT* __restrict__ C, int M, int N, int K) {
  __shared__ __attribute__((aligned(16))) f16 As[128][64];
  __shared__ __attribute__((aligned(16))) f16 Bs[128][64];
  const int gx = gridDim.x;
  const int nwg = gx * gridDim.y;
  const int flat = blockIdx.y * gx + blockIdx.x;
  const int q8 = nwg >> 3;
  const int id2 = (flat & 7) * q8 + (flat >> 3);
  const int bm = (id2 / gx) * 128, bn = (id2 % gx) * 128;
  const int tid = threadIdx.x;
  const int lane = tid & 63, wid = tid >> 6;
  const int wm = (wid >> 1) * 64, wn = (wid & 1) * 64;
  const int rr = lane & 15, rg = lane >> 4;
  const int sw = (((lane & 7) ^ (lane >> 3)) << 4);
  const int srw = lane >> 3;
  const char* Ab = (const char*)A + ((size_t)(bm + wid * 32 + srw) * K) * 2 + sw;
  const char* Bb = (const char*)Bt + ((size_t)(bn + wid * 32 + srw) * K) * 2 + sw;
  f32x4 acc[4][4] = {};
  for (int k0 = 0; k0 < K; k0 += 64) {
    __syncthreads();   // WAR: all waves done reading previous tile
#pragma unroll
    for (int g = 0; g < 4; ++g) {
      gload16(Ab + (size_t)(g * 8) * K * 2 + (size_t)k0 * 2,
              (char*)&As[0][0] + (wid * 32 + g * 8) * 128);
      gload16(Bb + (size_t)(g * 8) * K * 2 + (size_t)k0 * 2,
              (char*)&Bs[0][0] + (wid * 32 + g * 8) * 128);
    }
    __syncthreads();   // RAW: barrier drains vmcnt -> staged data visible
    f16x8 af[4][2], bf[4][2];
#pragma unroll
    for (int i = 0; i < 4; ++i)
#pragma unroll
      for (int kk = 0; kk < 2; ++kk) {
        af[i][kk] = *reinterpret_cast<const f16x8*>(
            (const char*)&As[0][0] + (wm + i * 16 + rr) * 128 +
            ((kk * 64 + rg * 16) ^ ((rr & 7) << 4)));
        bf[i][kk] = *reinterpret_cast<const f16x8*>(
            (const char*)&Bs[0][0] + (wn + i * 16 + rr) * 128 +
            ((kk * 64 + rg * 16) ^ ((rr & 7) << 4)));
      }
#pragma unroll
    for (int kk = 0; kk < 2; ++kk)
#pragma unroll
      for (int i = 0; i < 4; ++i)
#pragma unroll
        for (int j = 0; j < 4; ++j)
          acc[i][j] = __builtin_amdgcn_mfma_f32_16x16x32_f16(af[i][kk], bf[j][kk],
                                                             acc[i][j], 0, 0, 0);
  }
#pragma unroll
  for (int i = 0; i < 4; ++i)
#pragma unroll
    for (int j = 0; j < 4; ++j)
#pragma unroll
      for (int r = 0; r < 4; ++r)
        C[(size_t)(bm + wm + i * 16 + rg * 4 + r) * N + (bn + wn + j * 16 + rr)] =
            (OT)acc[i][j][r];
}

// ---------------- RMSNorm + RoPE for K only, f16 in / f16 out ----------------
// K is pre-scaled by LOG2E so QK^T logits are in log2 units.
__launch_bounds__(256, 4)
__global__ void norm_rope_k(const f16* __restrict__ qkv, const float* __restrict__ cosb,
                            const float* __restrict__ sinb, const float* __restrict__ ksc,
                            f16* __restrict__ kf) {
  int gw = blockIdx.x * 4 + (threadIdx.x >> 6);
  int lane = threadIdx.x & 63;
  int row = gw >> 2, c = gw & 3;
  int b = row >> 11, s = row & (S_ - 1);
  const f16* src = qkv + (size_t)row * NQKV_ + 2048 + c * 128;
  unsigned int u = *reinterpret_cast<const unsigned int*>(src + lane * 2);
  f16 p2[2]; __builtin_memcpy(p2, &u, 4);
  float vx = (float)p2[0], vy = (float)p2[1];
  float ss = vx * vx + vy * vy;
#pragma unroll
  for (int off = 32; off; off >>= 1) ss += __shfl_xor(ss, off);
  float inv = rsqrtf(ss * (1.0f / HD_) + EPS_);
  float x0 = vx * inv, x1 = vy * inv;
  int d0 = lane * 2;
  x0 *= (1.0f + ksc[d0]);
  x1 *= (1.0f + ksc[d0 + 1]);
  float y0 = __shfl_xor(x0, 16);
  float y1 = __shfl_xor(x1, 16);
  if (d0 < ROT_) {
    int dm = d0 & 31;
    float cs0 = cosb[s * 32 + dm],     sn0 = sinb[s * 32 + dm];
    float cs1 = cosb[s * 32 + dm + 1], sn1 = sinb[s * 32 + dm + 1];
    if (d0 < 32) { x0 = x0 * cs0 - y0 * sn0; x1 = x1 * cs1 - y1 * sn1; }
    else         { x0 = x0 * cs0 + y0 * sn0; x1 = x1 * cs1 + y1 * sn1; }
  }
  x0 *= LOG2E; x1 *= LOG2E;
  size_t idx = ((size_t)((b * KVH_ + c) * S_ + s)) * HD_ + d0;
  f16 o[2] = { (f16)x0, (f16)x1 };
  unsigned int pk; __builtin_memcpy(&pk, o, 4);
  *reinterpret_cast<unsigned int*>(kf + idx) = pk;
}

// ---------------- RMSNorm V + direct transpose write: qkv -> V^T [HD][S] ---------
// grid 512: id = (b*KVH+kvh)*64 + sblk. Block covers 32 s-rows x 128 d.
// FIX (r16 bug): 256 threads = 16 row-slots x 16 lane-chunks -> each thread now
// processes TWO rows (r and r+16), two independent 16-lane shuffle reductions.
// LDS tile [32][136] (272B row stride, 16B-aligned, 2-way max alias = free);
// write: thread t -> d = t>>1, 16 s-elems (two uint4), coalesced V^T stores.
__launch_bounds__(256, 4)
__global__ void norm_v_t(const f16* __restrict__ qkv, f16* __restrict__ vtb) {
  __shared__ __attribute__((aligned(16))) f16 tile[32][136];
  const int id = blockIdx.x;
  const int g = id >> 6;               // b*KVH_+kvh
  const int sblk = id & 63;
  const int b = g >> 2, kvh = g & 3;
  const int lane = threadIdx.x & 63, w = threadIdx.x >> 6;
  const int r = w * 4 + (lane >> 4);   // row slot [0,16)
  const int dl = (lane & 15) * 8;
#pragma unroll
  for (int half = 0; half < 2; ++half) {
    const int rr2 = r + half * 16;     // row within block [0,32)
    const int s = sblk * 32 + rr2;
    const f16* src = qkv + (size_t)(b * S_ + s) * NQKV_ + 2560 + kvh * 128 + dl;
    f16x8 u = *reinterpret_cast<const f16x8*>(src);
    float v[8];
    float ss = 0.f;
#pragma unroll
    for (int j = 0; j < 8; ++j) { v[j] = (float)u[j]; ss += v[j] * v[j]; }
#pragma unroll
    for (int off = 1; off < 16; off <<= 1) ss += __shfl_xor(ss, off);
    float inv = rsqrtf(ss * (1.0f / HD_) + EPS_);
    f16x8 o;
#pragma unroll
    for (int j = 0; j < 8; ++j) o[j] = (f16)(v[j] * inv);
    *reinterpret_cast<f16x8*>(&tile[rr2][dl]) = o;
  }
  __syncthreads();
  // transpose write: thread t -> d = t>>1, s-half = t&1 (16 consecutive s)
  const int d = threadIdx.x >> 1;
  const int sh = (threadIdx.x & 1) * 16;
  ushort_t tmp[16];
#pragma unroll
  for (int i = 0; i < 16; ++i)
    tmp[i] = *reinterpret_cast<const ushort_t*>(&tile[sh + i][d]);
  uint4 w0, w1;
  __builtin_memcpy(&w0, tmp, 16);
  __builtin_memcpy(&w1, tmp + 8, 16);
  f16* dst = vtb + (size_t)g * HD_ * S_ + (size_t)d * S_ + sblk * 32 + sh;
  *reinterpret_cast<uint4*>(dst)     = w0;
  *reinterpret_cast<uint4*>(dst + 8) = w1;
}

// ---------------- flash attention v8b: swapped QK^T, in-register softmax ----------
// 512 blocks x 256 thr (4 waves x 32 q-rows). KVBLK=64 double-buffered staging via
// global_load_lds w16 (XOR swizzle ^((row&7)<<4)). Swapped 32x32 MFMA QK^T -> lane
// owns q=lane&31; in-lane softmax + one shfl_xor(32); P->B-frag via cvt_pkrtz +
// v_permlane32_swap_b32 (T12); PV = mfma(V^T-frag, P^T-frag). Defer-max, log2 domain.
// NOTE: needs launch_bounds(256,2) — acc uses 64 AGPR + ~108 VGPR (unified file);
// (256,4) caps at 128 and spills to scratch (round-13 regression: 65 -> 146 us).
__launch_bounds__(256, 2)
__global__ void flash_attn(const f16* __restrict__ qkv, const float* __restrict__ cosb,
                           const float* __restrict__ sinb, const float* __restrict__ qsc,
                           const f16* __restrict__ kfp, const f16* __restrict__ vt,
                           f16* __restrict__ ctxf) {
  __shared__ __attribute__((aligned(16))) f16 Ks[2][KVBLK][128];   // 32 KB
  __shared__ __attribute__((aligned(16))) f16 Vs[2][128][KVBLK];   // 32 KB
  const int id = blockIdx.x;
  const int g8 = id & 7, rest = id >> 3;          // rest in [0,64)
  const int b = g8 >> 2, kvh = g8 & 3;
  int hh, qtile;
  if (rest < 32) { hh = rest >> 3; qtile = 8 + (rest & 7); }     // heavy: 18 tiles
  else { int lv = rest - 32; hh = lv >> 3; qtile = lv & 7; }     // light: 2..16
  const int h = kvh * 4 + hh;
  const int lane = threadIdx.x & 63, w = threadIdx.x >> 6;
  const int ql = lane & 31;          // this lane's q column
  const int hi = lane >> 5;          // half (0/1)
  const int qBase = qtile * QBLK;
  const int qw = qBase + w * 32;
  const int q = qw + ql;             // sequence position
  const f16* Kh = kfp + (size_t)(b * KVH_ + kvh) * S_ * HD_;
  const f16* Vh = vt  + (size_t)(b * KVH_ + kvh) * HD_ * S_;

  // ---- q prep: lane loads 64 f16 of row q (d = kk*16 + hi*8 + j), rmsnorm,
  //      scale, rope (lane-local pairs kk<->kk+2), cvt to B-frag layout ----
  f16x8 qf[8];
  {
    const f16* qrow = qkv + (size_t)(b * S_ + q) * NQKV_ + h * HD_;
    float qv[8][8];
    float ssq = 0.f;
#pragma unroll
    for (int kk = 0; kk < 8; ++kk) {
      f16x8 u = *reinterpret_cast<const f16x8*>(qrow + kk * 16 + hi * 8);
#pragma unroll
      for (int j = 0; j < 8; ++j) {
        qv[kk][j] = (float)u[j];
        ssq += qv[kk][j] * qv[kk][j];
      }
    }
    ssq += __shfl_xor(ssq, 32);   // partner lane has the other 64 dims
    float inv = rsqrtf(ssq * (1.0f / HD_) + EPS_);
#pragma unroll
    for (int kk = 0; kk < 8; ++kk)
#pragma unroll
      for (int j = 0; j < 8; ++j)
        qv[kk][j] *= inv * (1.0f + qsc[kk * 16 + hi * 8 + j]);
    const float* cs = cosb + (size_t)q * 32;
    const float* sn = sinb + (size_t)q * 32;
#pragma unroll
    for (int kk = 0; kk < 2; ++kk)
#pragma unroll
      for (int j = 0; j < 8; ++j) {
        int d = kk * 16 + hi * 8 + j;          // in [0,32)
        float c = cs[d], s_ = sn[d];
        float x0 = qv[kk][j], x1 = qv[kk + 2][j];
        qv[kk][j]     = x0 * c - x1 * s_;
        qv[kk + 2][j] = x1 * c + x0 * s_;
      }
#pragma unroll
    for (int kk = 0; kk < 8; ++kk)
#pragma unroll
      for (int j = 0; j < 8; ++j)
        qf[kk][j] = (f16)qv[kk][j];
  }

  f32x16 acc[4] = {};
  float m_run = NINF, msafe = 0.f, l_run = 0.f;

  int kvStart = qBase - (WINDOW_ - 1);
  if (kvStart < 0) kvStart = 0;
  kvStart &= ~(KVBLK - 1);
  const int ntile = (qBase + QBLK - kvStart) >> 6;

  const int k_r0 = lane >> 4;          // 0..3
  const int k_cb = (lane & 15) * 16;
  const int v_r0 = lane >> 3;          // 0..7
  const int v_cb = (lane & 7) * 16;

#define STAGE(bufs, key0_)                                                           \
  do {                                                                               \
    _Pragma("unroll")                                                                \
    for (int gg = 0; gg < 4; ++gg) {                                                 \
      int krow = gg * 4 + k_r0;                                                      \
      gload16((const char*)Kh + (size_t)((key0_) + w * 16 + krow) * 256 +            \
                  (k_cb ^ ((krow & 7) << 4)),                                        \
              (char*)&Ks[bufs][0][0] + (w * 16 + gg * 4) * 256);                     \
      int vrow = gg * 8 + v_r0;                                                      \
      gload16((const char*)Vh + (size_t)(w * 32 + vrow) * (S_ * 2) +                 \
                  (size_t)(key0_) * 2 + (v_cb ^ ((vrow & 7) << 4)),                  \
              (char*)&Vs[bufs][0][0] + (w * 32 + gg * 8) * 128);                     \
    }                                                                                \
  } while (0)

  STAGE(0, kvStart);
  __syncthreads();

  for (int t = 0; t < ntile; ++t) {
    const int key0 = kvStart + t * KVBLK;
    const int buf = t & 1;
    if (t + 1 < ntile) STAGE(buf ^ 1, key0 + KVBLK);

    const bool live = (key0 <= qw + 31) && (key0 + 63 >= qw - (WINDOW_ - 1));
    if (live) {
      // ---- QK^T swapped: S^T[key][q], lane holds q=ql, keys via reg map ----
      f32x16 st[2];
#pragma unroll
      for (int kt = 0; kt < 2; ++kt) {
        const int rt = kt * 32 + ql;
        const char* kbase = (const char*)&Ks[buf][0][0] + rt * 256;
        const int swz = (rt & 7) << 4;
        f32x16 s = {};
#pragma unroll
        for (int kk = 0; kk < 8; ++kk) {
          f16x8 kfr = *reinterpret_cast<const f16x8*>(kbase + ((kk * 32 + hi * 16) ^ swz));
          s = __builtin_amdgcn_mfma_f32_32x32x16_f16(kfr, qf[kk], s, 0, 0, 0);
        }
        st[kt] = s;
      }

      // ---- mask (skipped for interior tiles); key = key0+kt*32+(r&3)+8(r>>2)+4hi ----
      const bool interior = (key0 + 63 <= qw) && (key0 >= qw - 992);
      if (!interior) {
#pragma unroll
        for (int kt = 0; kt < 2; ++kt)
#pragma unroll
          for (int r = 0; r < 16; ++r) {
            int kj = key0 + kt * 32 + ((r & 3) + 8 * (r >> 2) + 4 * hi);
            bool valid = (kj <= q) && (q - kj < WINDOW_);
            if (!valid) st[kt][r] = NINF;
          }
      }

      // ---- in-lane row max + one cross-half swap ----
      float tm = st[0][0];
#pragma unroll
      for (int r = 1; r < 16; ++r) tm = fmaxf(tm, st[0][r]);
#pragma unroll
      for (int r = 0; r < 16; ++r) tm = fmaxf(tm, st[1][r]);
      tm = fmaxf(tm, __shfl_xor(tm, 32));

      // ---- defer-max rescale ----
      bool defer = (tm - m_run <= DEFER_THR);
      if (!__all(defer)) {
        float mn = fmaxf(m_run, tm);
        float alpha = (m_run == NINF) ? 0.f : EXP2F(m_run - mn);
        m_run = mn;
        msafe = (mn == NINF) ? 0.f : mn;
#pragma unroll
        for (int dt = 0; dt < 4; ++dt)
#pragma unroll
          for (int r = 0; r < 16; ++r) acc[dt][r] *= alpha;
        l_run *= alpha;
      }
      // ---- exp (log2 domain) + row-sum ----
      float ps = 0.f;
#pragma unroll
      for (int kt = 0; kt < 2; ++kt)
#pragma unroll
        for (int r = 0; r < 16; ++r) {
          float p = EXP2F(st[kt][r] - msafe);
          st[kt][r] = p;
          ps += p;
        }
      ps += __shfl_xor(ps, 32);
      l_run += ps;

      // ---- P -> B-fragments in-register (cvt_pk + permlane32_swap) ----
      f16x8 pf[4];
#pragma unroll
      for (int ks = 0; ks < 4; ++ks) {
        const int kt = ks >> 1, rb = (ks & 1) * 8;
        int w0 = cvtpk_i(st[kt][rb + 0], st[kt][rb + 1]);
        int w2 = cvtpk_i(st[kt][rb + 4], st[kt][rb + 5]);
        asm volatile("v_permlane32_swap_b32 %0, %1" : "+v"(w0), "+v"(w2));
        int w1 = cvtpk_i(st[kt][rb + 2], st[kt][rb + 3]);
        int w3 = cvtpk_i(st[kt][rb + 6], st[kt][rb + 7]);
        asm volatile("v_permlane32_swap_b32 %0, %1" : "+v"(w1), "+v"(w3));
        int wi[4] = { w0, w1, w2, w3 };
        __builtin_memcpy(&pf[ks], wi, 16);
      }

      // ---- PV swapped: ctx^T[d][q] += V^T-frag x P^T-frag ----
      __builtin_amdgcn_s_setprio(1);
#pragma unroll
      for (int dt = 0; dt < 4; ++dt) {
        const int d = dt * 32 + ql;
        const char* vbase = (const char*)&Vs[buf][0][0] + d * 128;
        const int swz = (d & 7) << 4;
#pragma unroll
        for (int ks = 0; ks < 4; ++ks) {
          f16x8 vf = *reinterpret_cast<const f16x8*>(vbase + ((ks * 32 + hi * 16) ^ swz));
          acc[dt] = __builtin_amdgcn_mfma_f32_32x32x16_f16(vf, pf[ks], acc[dt], 0, 0, 0);
        }
      }
      __builtin_amdgcn_s_setprio(0);
    }

    __syncthreads();   // drains prefetch vmcnt + all waves done with buf
  }
#undef STAGE

  // ---- epilogue: lane owns q; d = dt*32 + 8*g + 4*hi + r -> 8B packed stores ----
  const float rinv = 1.0f / l_run;
  f16* orow = ctxf + (size_t)(b * S_ + q) * D_ + h * HD_;
#pragma unroll
  for (int dt = 0; dt < 4; ++dt)
#pragma unroll
    for (int g = 0; g < 4; ++g) {
      f16x4 o;
#pragma unroll
      for (int r = 0; r < 4; ++r) o[r] = (f16)(acc[dt][g * 4 + r] * rinv);
      *reinterpret_cast<f16x4*>(orow + dt * 32 + 8 * g + 4 * hi) = o;
    }
}

extern "C" void kernel_launch(void* const* d_in, const int* in_sizes, int n_in,
                              void* d_out, int out_size, void* d_ws, size_t ws_size,
                              hipStream_t stream) {
  const float* x    = (const float*)d_in[0];
  // d_in[1] = mask (recomputed analytically)
  const float* cosb = (const float*)d_in[2];
  const float* sinb = (const float*)d_in[3];
  const float* Wq   = (const float*)d_in[4];
  const float* Wk   = (const float*)d_in[5];
  const float* Wv   = (const float*)d_in[6];
  const float* Wo   = (const float*)d_in[7];
  const float* qsc  = (const float*)d_in[8];
  const float* ksc  = (const float*)d_in[9];
  float* out = (float*)d_out;

  char* ws = (char*)d_ws;
  const size_t MB = 1ull << 20;
  // [0,16)  xh fp16         -> after gemm0 reused: ctxf fp16
  // [16,28) wqkvT fp16      -> after gemm0 reused: kf[16,20) vtb[24,28)
  // [28,36) woT fp16
  // [36,60) qkv fp16
  f16* xh    = (f16*)(ws + 0 * MB);
  f16* ctxf  = (f16*)(ws + 0 * MB);
  f16* wqkvT = (f16*)(ws + 16 * MB);
  f16* kf    = (f16*)(ws + 16 * MB);
  f16* vtb   = (f16*)(ws + 24 * MB);
  f16* woT   = (f16*)(ws + 28 * MB);
  f16* qkvh  = (f16*)(ws + 36 * MB);

  prep<<<dim3(14336), 256, 0, stream>>>(x, xh, Wq, Wk, Wv, Wo, wqkvT, woT);
  gemm_f16<f16><<<dim3(NQKV_ / 128, M_ / 128), 256, 0, stream>>>(
      xh, wqkvT, qkvh, M_, NQKV_, D_);
  norm_rope_k<<<dim3(M_ * 4 / 4), 256, 0, stream>>>(qkvh, cosb, sinb, ksc, kf);
  norm_v_t<<<dim3(B_ * KVH_ * (S_ / 32)), 256, 0, stream>>>(qkvh, vtb);
  flash_attn<<<dim3((S_ / QBLK) * H_ * B_), 256, 0, stream>>>(
      qkvh, cosb, sinb, qsc, kf, vtb, ctxf);
  gemm_f16<float><<<dim3(D_ / 128, M_ / 128), 256, 0, stream>>>(
      ctxf, woT, out, M_, D_, D_);
}

// Round 18
// 192.375 us; speedup vs baseline: 1.4456x; 1.0127x over previous
//
#include <hip/hip_runtime.h>
#include <stdint.h>

#define B_ 2
#define S_ 2048
#define D_ 2048
#define H_ 16
#define KVH_ 4
#define HD_ 128
#define ROT_ 64
#define WINDOW_ 1024
#define EPS_ 1e-6f
#define M_ (B_ * S_)
#define NQKV_ 3072

#define QBLK 128
#define KVBLK 64
#define LOG2E 1.44269504088896340736f
#define DEFER_THR 8.0f

typedef unsigned short ushort_t;
typedef _Float16 f16;
typedef float f32x4 __attribute__((ext_vector_type(4)));
typedef float f32x16 __attribute__((ext_vector_type(16)));
typedef f16 f16x4 __attribute__((ext_vector_type(4)));
typedef f16 f16x8 __attribute__((ext_vector_type(8)));

#define NINF (-__builtin_inff())
#define EXP2F(x) __builtin_exp2f(x)

// async global->LDS, 16B per lane. dst must be wave-uniform; HW adds lane*16.
__device__ __forceinline__ void gload16(const void* g, void* l) {
  __builtin_amdgcn_global_load_lds(
      (const __attribute__((address_space(1))) void*)g,
      (__attribute__((address_space(3))) void*)l, 16, 0, 0);
}

// pack 2 f32 -> 1 u32 of 2 fp16 (rtz)
__device__ __forceinline__ int cvtpk_i(float a, float b) {
  auto h = __builtin_amdgcn_cvt_pkrtz(a, b);
  int r; __builtin_memcpy(&r, &h, 4); return r;
}

// ---------------- fused prep: x cast (f32->f16) + 4 weight transposes ----------
// grid 14336 x 256: [0,4096) cast x; [4096,8192) Wq^T; [8192,9216) Wk^T;
// [9216,10240) Wv^T; [10240,14336) Wo^T. One launch replaces 5.
__launch_bounds__(256, 4)
__global__ void prep(const float* __restrict__ x, f16* __restrict__ xh,
                     const float* __restrict__ Wq, const float* __restrict__ Wk,
                     const float* __restrict__ Wv, const float* __restrict__ Wo,
                     f16* __restrict__ wqkvT, f16* __restrict__ woT) {
  __shared__ float tile[32][33];
  int id = blockIdx.x;
  if (id < 4096) {   // cast path: 8 f32 -> 8 f16 per thread
    int i = id * 256 + threadIdx.x;
    float4 a = reinterpret_cast<const float4*>(x)[i * 2];
    float4 b = reinterpret_cast<const float4*>(x)[i * 2 + 1];
    f16x8 o = { (f16)a.x, (f16)a.y, (f16)a.z, (f16)a.w,
                (f16)b.x, (f16)b.y, (f16)b.z, (f16)b.w };
    reinterpret_cast<f16x8*>(xh)[i] = o;
    return;
  }
  id -= 4096;
  const float* src; f16* dst; int C, bx, by;
  if (id < 4096)      { src = Wq; dst = wqkvT;                      C = 2048; bx = id & 63; by = id >> 6; }
  else if (id < 5120) { id -= 4096; src = Wk; dst = wqkvT + (size_t)2048 * D_; C = 512; bx = id & 15; by = id >> 4; }
  else if (id < 6144) { id -= 5120; src = Wv; dst = wqkvT + (size_t)2560 * D_; C = 512; bx = id & 15; by = id >> 4; }
  else                { id -= 6144; src = Wo; dst = woT;            C = 2048; bx = id & 63; by = id >> 6; }
  const int c0 = bx * 32, r0 = by * 32;
  const int tx = threadIdx.x & 31, ty = threadIdx.x >> 5;
#pragma unroll
  for (int i = 0; i < 32; i += 8)
    tile[ty + i][tx] = src[(size_t)(r0 + ty + i) * C + c0 + tx];
  __syncthreads();
#pragma unroll
  for (int i = 0; i < 32; i += 8)
    dst[(size_t)(c0 + ty + i) * D_ + r0 + tx] = (f16)tile[tx][ty + i];
}

// ---------------- fp16 GEMM: single-buffered m97 structure, templated output ----
template<typename OT>
__launch_bounds__(256, 2)
__global__ void gemm_f16(const f16* __restrict__ A, const f16* __restrict__ Bt,
                         OT* __restrict__ C, int M, int N, int K) {
  __shared__ __attribute__((aligned(16))) f16 As[128][64];
  __shared__ __attribute__((aligned(16))) f16 Bs[128][64];
  const int gx = gridDim.x;
  const int nwg = gx * gridDim.y;
  const int flat = blockIdx.y * gx + blockIdx.x;
  const int q8 = nwg >> 3;
  const int id2 = (flat & 7) * q8 + (flat >> 3);
  const int bm = (id2 / gx) * 128, bn = (id2 % gx) * 128;
  const int tid = threadIdx.x;
  const int lane = tid & 63, wid = tid >> 6;
  const int wm = (wid >> 1) * 64, wn = (wid & 1) * 64;
  const int rr = lane & 15, rg = lane >> 4;
  const int sw = (((lane & 7) ^ (lane >> 3)) << 4);
  const int srw = lane >> 3;
  const char* Ab = (const char*)A + ((size_t)(bm + wid * 32 + srw) * K) * 2 + sw;
  const char* Bb = (const char*)Bt + ((size_t)(bn + wid * 32 + srw) * K) * 2 + sw;
  f32x4 acc[4][4] = {};
  for (int k0 = 0; k0 < K; k0 += 64) {
    __syncthreads();   // WAR: all waves done reading previous tile
#pragma unroll
    for (int g = 0; g < 4; ++g) {
      gload16(Ab + (size_t)(g * 8) * K * 2 + (size_t)k0 * 2,
              (char*)&As[0][0] + (wid * 32 + g * 8) * 128);
      gload16(Bb + (size_t)(g * 8) * K * 2 + (size_t)k0 * 2,
              (char*)&Bs[0][0] + (wid * 32 + g * 8) * 128);
    }
    __syncthreads();   // RAW: barrier drains vmcnt -> staged data visible
    f16x8 af[4][2], bf[4][2];
#pragma unroll
    for (int i = 0; i < 4; ++i)
#pragma unroll
      for (int kk = 0; kk < 2; ++kk) {
        af[i][kk] = *reinterpret_cast<const f16x8*>(
            (const char*)&As[0][0] + (wm + i * 16 + rr) * 128 +
            ((kk * 64 + rg * 16) ^ ((rr & 7) << 4)));
        bf[i][kk] = *reinterpret_cast<const f16x8*>(
            (const char*)&Bs[0][0] + (wn + i * 16 + rr) * 128 +
            ((kk * 64 + rg * 16) ^ ((rr & 7) << 4)));
      }
#pragma unroll
    for (int kk = 0; kk < 2; ++kk)
#pragma unroll
      for (int i = 0; i < 4; ++i)
#pragma unroll
        for (int j = 0; j < 4; ++j)
          acc[i][j] = __builtin_amdgcn_mfma_f32_16x16x32_f16(af[i][kk], bf[j][kk],
                                                             acc[i][j], 0, 0, 0);
  }
#pragma unroll
  for (int i = 0; i < 4; ++i)
#pragma unroll
    for (int j = 0; j < 4; ++j)
#pragma unroll
      for (int r = 0; r < 4; ++r)
        C[(size_t)(bm + wm + i * 16 + rg * 4 + r) * N + (bn + wn + j * 16 + rr)] =
            (OT)acc[i][j][r];
}

// ---------------- fused norm: K rmsnorm+rope ([0,4096)) + V rmsnorm+transpose ----
// K path: one wave per (row, k-head) chunk; K pre-scaled by LOG2E (log2-domain
// logits). V path (ids 4096..4607): 32 s-rows x 128 d per block, each thread does
// TWO rows (16-lane shuffle rmsnorm), LDS tile [32][136], coalesced V^T stores.
__launch_bounds__(256, 4)
__global__ void norm_kv(const f16* __restrict__ qkv, const float* __restrict__ cosb,
                        const float* __restrict__ sinb, const float* __restrict__ ksc,
                        f16* __restrict__ kf, f16* __restrict__ vtb) {
  __shared__ __attribute__((aligned(16))) f16 tile[32][136];
  const int bid = blockIdx.x;
  if (bid < 4096) {
    // ---- K path (exact norm_rope_k body) ----
    int gw = bid * 4 + (threadIdx.x >> 6);
    int lane = threadIdx.x & 63;
    int row = gw >> 2, c = gw & 3;
    int b = row >> 11, s = row & (S_ - 1);
    const f16* src = qkv + (size_t)row * NQKV_ + 2048 + c * 128;
    unsigned int u = *reinterpret_cast<const unsigned int*>(src + lane * 2);
    f16 p2[2]; __builtin_memcpy(p2, &u, 4);
    float vx = (float)p2[0], vy = (float)p2[1];
    float ss = vx * vx + vy * vy;
#pragma unroll
    for (int off = 32; off; off >>= 1) ss += __shfl_xor(ss, off);
    float inv = rsqrtf(ss * (1.0f / HD_) + EPS_);
    float x0 = vx * inv, x1 = vy * inv;
    int d0 = lane * 2;
    x0 *= (1.0f + ksc[d0]);
    x1 *= (1.0f + ksc[d0 + 1]);
    float y0 = __shfl_xor(x0, 16);
    float y1 = __shfl_xor(x1, 16);
    if (d0 < ROT_) {
      int dm = d0 & 31;
      float cs0 = cosb[s * 32 + dm],     sn0 = sinb[s * 32 + dm];
      float cs1 = cosb[s * 32 + dm + 1], sn1 = sinb[s * 32 + dm + 1];
      if (d0 < 32) { x0 = x0 * cs0 - y0 * sn0; x1 = x1 * cs1 - y1 * sn1; }
      else         { x0 = x0 * cs0 + y0 * sn0; x1 = x1 * cs1 + y1 * sn1; }
    }
    x0 *= LOG2E; x1 *= LOG2E;
    size_t idx = ((size_t)((b * KVH_ + c) * S_ + s)) * HD_ + d0;
    f16 o[2] = { (f16)x0, (f16)x1 };
    unsigned int pk; __builtin_memcpy(&pk, o, 4);
    *reinterpret_cast<unsigned int*>(kf + idx) = pk;
    return;
  }
  // ---- V path (exact norm_v_t body, id2 = bid - 4096) ----
  const int id2 = bid - 4096;
  const int g = id2 >> 6;               // b*KVH_+kvh
  const int sblk = id2 & 63;
  const int b = g >> 2, kvh = g & 3;
  const int lane = threadIdx.x & 63, w = threadIdx.x >> 6;
  const int r = w * 4 + (lane >> 4);   // row slot [0,16)
  const int dl = (lane & 15) * 8;
#pragma unroll
  for (int half = 0; half < 2; ++half) {
    const int rr2 = r + half * 16;     // row within block [0,32)
    const int s = sblk * 32 + rr2;
    const f16* src = qkv + (size_t)(b * S_ + s) * NQKV_ + 2560 + kvh * 128 + dl;
    f16x8 u = *reinterpret_cast<const f16x8*>(src);
    float v[8];
    float ss = 0.f;
#pragma unroll
    for (int j = 0; j < 8; ++j) { v[j] = (float)u[j]; ss += v[j] * v[j]; }
#pragma unroll
    for (int off = 1; off < 16; off <<= 1) ss += __shfl_xor(ss, off);
    float inv = rsqrtf(ss * (1.0f / HD_) + EPS_);
    f16x8 o;
#pragma unroll
    for (int j = 0; j < 8; ++j) o[j] = (f16)(v[j] * inv);
    *reinterpret_cast<f16x8*>(&tile[rr2][dl]) = o;
  }
  __syncthreads();
  // transpose write: thread t -> d = t>>1, s-half = t&1 (16 consecutive s)
  const int d = threadIdx.x >> 1;
  const int sh = (threadIdx.x & 1) * 16;
  ushort_t tmp[16];
#pragma unroll
  for (int i = 0; i < 16; ++i)
    tmp[i] = *reinterpret_cast<const ushort_t*>(&tile[sh + i][d]);
  uint4 w0, w1;
  __builtin_memcpy(&w0, tmp, 16);
  __builtin_memcpy(&w1, tmp + 8, 16);
  f16* dst = vtb + (size_t)g * HD_ * S_ + (size_t)d * S_ + sblk * 32 + sh;
  *reinterpret_cast<uint4*>(dst)     = w0;
  *reinterpret_cast<uint4*>(dst + 8) = w1;
}

// ---------------- flash attention v8b: swapped QK^T, in-register softmax ----------
// 512 blocks x 256 thr (4 waves x 32 q-rows). KVBLK=64 double-buffered staging via
// global_load_lds w16 (XOR swizzle ^((row&7)<<4)). Swapped 32x32 MFMA QK^T -> lane
// owns q=lane&31; in-lane softmax + one shfl_xor(32); P->B-frag via cvt_pkrtz +
// v_permlane32_swap_b32 (T12); PV = mfma(V^T-frag, P^T-frag). Defer-max, log2 domain.
// NOTE: needs launch_bounds(256,2) — acc uses 64 AGPR + ~108 VGPR (unified file);
// (256,4) caps at 128 and spills to scratch (round-13 regression: 65 -> 146 us).
__launch_bounds__(256, 2)
__global__ void flash_attn(const f16* __restrict__ qkv, const float* __restrict__ cosb,
                           const float* __restrict__ sinb, const float* __restrict__ qsc,
                           const f16* __restrict__ kfp, const f16* __restrict__ vt,
                           f16* __restrict__ ctxf) {
  __shared__ __attribute__((aligned(16))) f16 Ks[2][KVBLK][128];   // 32 KB
  __shared__ __attribute__((aligned(16))) f16 Vs[2][128][KVBLK];   // 32 KB
  const int id = blockIdx.x;
  const int g8 = id & 7, rest = id >> 3;          // rest in [0,64)
  const int b = g8 >> 2, kvh = g8 & 3;
  int hh, qtile;
  if (rest < 32) { hh = rest >> 3; qtile = 8 + (rest & 7); }     // heavy: 18 tiles
  else { int lv = rest - 32; hh = lv >> 3; qtile = lv & 7; }     // light: 2..16
  const int h = kvh * 4 + hh;
  const int lane = threadIdx.x & 63, w = threadIdx.x >> 6;
  const int ql = lane & 31;          // this lane's q column
  const int hi = lane >> 5;          // half (0/1)
  const int qBase = qtile * QBLK;
  const int qw = qBase + w * 32;
  const int q = qw + ql;             // sequence position
  const f16* Kh = kfp + (size_t)(b * KVH_ + kvh) * S_ * HD_;
  const f16* Vh = vt  + (size_t)(b * KVH_ + kvh) * HD_ * S_;

  // ---- q prep: lane loads 64 f16 of row q (d = kk*16 + hi*8 + j), rmsnorm,
  //      scale, rope (lane-local pairs kk<->kk+2), cvt to B-frag layout ----
  f16x8 qf[8];
  {
    const f16* qrow = qkv + (size_t)(b * S_ + q) * NQKV_ + h * HD_;
    float qv[8][8];
    float ssq = 0.f;
#pragma unroll
    for (int kk = 0; kk < 8; ++kk) {
      f16x8 u = *reinterpret_cast<const f16x8*>(qrow + kk * 16 + hi * 8);
#pragma unroll
      for (int j = 0; j < 8; ++j) {
        qv[kk][j] = (float)u[j];
        ssq += qv[kk][j] * qv[kk][j];
      }
    }
    ssq += __shfl_xor(ssq, 32);   // partner lane has the other 64 dims
    float inv = rsqrtf(ssq * (1.0f / HD_) + EPS_);
#pragma unroll
    for (int kk = 0; kk < 8; ++kk)
#pragma unroll
      for (int j = 0; j < 8; ++j)
        qv[kk][j] *= inv * (1.0f + qsc[kk * 16 + hi * 8 + j]);
    const float* cs = cosb + (size_t)q * 32;
    const float* sn = sinb + (size_t)q * 32;
#pragma unroll
    for (int kk = 0; kk < 2; ++kk)
#pragma unroll
      for (int j = 0; j < 8; ++j) {
        int d = kk * 16 + hi * 8 + j;          // in [0,32)
        float c = cs[d], s_ = sn[d];
        float x0 = qv[kk][j], x1 = qv[kk + 2][j];
        qv[kk][j]     = x0 * c - x1 * s_;
        qv[kk + 2][j] = x1 * c + x0 * s_;
      }
#pragma unroll
    for (int kk = 0; kk < 8; ++kk)
#pragma unroll
      for (int j = 0; j < 8; ++j)
        qf[kk][j] = (f16)qv[kk][j];
  }

  f32x16 acc[4] = {};
  float m_run = NINF, msafe = 0.f, l_run = 0.f;

  int kvStart = qBase - (WINDOW_ - 1);
  if (kvStart < 0) kvStart = 0;
  kvStart &= ~(KVBLK - 1);
  const int ntile = (qBase + QBLK - kvStart) >> 6;

  const int k_r0 = lane >> 4;          // 0..3
  const int k_cb = (lane & 15) * 16;
  const int v_r0 = lane >> 3;          // 0..7
  const int v_cb = (lane & 7) * 16;

#define STAGE(bufs, key0_)                                                           \
  do {                                                                               \
    _Pragma("unroll")                                                                \
    for (int gg = 0; gg < 4; ++gg) {                                                 \
      int krow = gg * 4 + k_r0;                                                      \
      gload16((const char*)Kh + (size_t)((key0_) + w * 16 + krow) * 256 +            \
                  (k_cb ^ ((krow & 7) << 4)),                                        \
              (char*)&Ks[bufs][0][0] + (w * 16 + gg * 4) * 256);                     \
      int vrow = gg * 8 + v_r0;                                                      \
      gload16((const char*)Vh + (size_t)(w * 32 + vrow) * (S_ * 2) +                 \
                  (size_t)(key0_) * 2 + (v_cb ^ ((vrow & 7) << 4)),                  \
              (char*)&Vs[bufs][0][0] + (w * 32 + gg * 8) * 128);                     \
    }                                                                                \
  } while (0)

  STAGE(0, kvStart);
  __syncthreads();

  for (int t = 0; t < ntile; ++t) {
    const int key0 = kvStart + t * KVBLK;
    const int buf = t & 1;
    if (t + 1 < ntile) STAGE(buf ^ 1, key0 + KVBLK);

    const bool live = (key0 <= qw + 31) && (key0 + 63 >= qw - (WINDOW_ - 1));
    if (live) {
      // ---- QK^T swapped: S^T[key][q], lane holds q=ql, keys via reg map ----
      f32x16 st[2];
#pragma unroll
      for (int kt = 0; kt < 2; ++kt) {
        const int rt = kt * 32 + ql;
        const char* kbase = (const char*)&Ks[buf][0][0] + rt * 256;
        const int swz = (rt & 7) << 4;
        f32x16 s = {};
#pragma unroll
        for (int kk = 0; kk < 8; ++kk) {
          f16x8 kfr = *reinterpret_cast<const f16x8*>(kbase + ((kk * 32 + hi * 16) ^ swz));
          s = __builtin_amdgcn_mfma_f32_32x32x16_f16(kfr, qf[kk], s, 0, 0, 0);
        }
        st[kt] = s;
      }

      // ---- mask (skipped for interior tiles); key = key0+kt*32+(r&3)+8(r>>2)+4hi ----
      const bool interior = (key0 + 63 <= qw) && (key0 >= qw - 992);
      if (!interior) {
#pragma unroll
        for (int kt = 0; kt < 2; ++kt)
#pragma unroll
          for (int r = 0; r < 16; ++r) {
            int kj = key0 + kt * 32 + ((r & 3) + 8 * (r >> 2) + 4 * hi);
            bool valid = (kj <= q) && (q - kj < WINDOW_);
            if (!valid) st[kt][r] = NINF;
          }
      }

      // ---- in-lane row max + one cross-half swap ----
      float tm = st[0][0];
#pragma unroll
      for (int r = 1; r < 16; ++r) tm = fmaxf(tm, st[0][r]);
#pragma unroll
      for (int r = 0; r < 16; ++r) tm = fmaxf(tm, st[1][r]);
      tm = fmaxf(tm, __shfl_xor(tm, 32));

      // ---- defer-max rescale ----
      bool defer = (tm - m_run <= DEFER_THR);
      if (!__all(defer)) {
        float mn = fmaxf(m_run, tm);
        float alpha = (m_run == NINF) ? 0.f : EXP2F(m_run - mn);
        m_run = mn;
        msafe = (mn == NINF) ? 0.f : mn;
#pragma unroll
        for (int dt = 0; dt < 4; ++dt)
#pragma unroll
          for (int r = 0; r < 16; ++r) acc[dt][r] *= alpha;
        l_run *= alpha;
      }
      // ---- exp (log2 domain) + row-sum ----
      float ps = 0.f;
#pragma unroll
      for (int kt = 0; kt < 2; ++kt)
#pragma unroll
        for (int r = 0; r < 16; ++r) {
          float p = EXP2F(st[kt][r] - msafe);
          st[kt][r] = p;
          ps += p;
        }
      ps += __shfl_xor(ps, 32);
      l_run += ps;

      // ---- P -> B-fragments in-register (cvt_pk + permlane32_swap) ----
      f16x8 pf[4];
#pragma unroll
      for (int ks = 0; ks < 4; ++ks) {
        const int kt = ks >> 1, rb = (ks & 1) * 8;
        int w0 = cvtpk_i(st[kt][rb + 0], st[kt][rb + 1]);
        int w2 = cvtpk_i(st[kt][rb + 4], st[kt][rb + 5]);
        asm volatile("v_permlane32_swap_b32 %0, %1" : "+v"(w0), "+v"(w2));
        int w1 = cvtpk_i(st[kt][rb + 2], st[kt][rb + 3]);
        int w3 = cvtpk_i(st[kt][rb + 6], st[kt][rb + 7]);
        asm volatile("v_permlane32_swap_b32 %0, %1" : "+v"(w1), "+v"(w3));
        int wi[4] = { w0, w1, w2, w3 };
        __builtin_memcpy(&pf[ks], wi, 16);
      }

      // ---- PV swapped: ctx^T[d][q] += V^T-frag x P^T-frag ----
      __builtin_amdgcn_s_setprio(1);
#pragma unroll
      for (int dt = 0; dt < 4; ++dt) {
        const int d = dt * 32 + ql;
        const char* vbase = (const char*)&Vs[buf][0][0] + d * 128;
        const int swz = (d & 7) << 4;
#pragma unroll
        for (int ks = 0; ks < 4; ++ks) {
          f16x8 vf = *reinterpret_cast<const f16x8*>(vbase + ((ks * 32 + hi * 16) ^ swz));
          acc[dt] = __builtin_amdgcn_mfma_f32_32x32x16_f16(vf, pf[ks], acc[dt], 0, 0, 0);
        }
      }
      __builtin_amdgcn_s_setprio(0);
    }

    __syncthreads();   // drains prefetch vmcnt + all waves done with buf
  }
#undef STAGE

  // ---- epilogue: lane owns q; d = dt*32 + 8*g + 4*hi + r -> 8B packed stores ----
  const float rinv = 1.0f / l_run;
  f16* orow = ctxf + (size_t)(b * S_ + q) * D_ + h * HD_;
#pragma unroll
  for (int dt = 0; dt < 4; ++dt)
#pragma unroll
    for (int g = 0; g < 4; ++g) {
      f16x4 o;
#pragma unroll
      for (int r = 0; r < 4; ++r) o[r] = (f16)(acc[dt][g * 4 + r] * rinv);
      *reinterpret_cast<f16x4*>(orow + dt * 32 + 8 * g + 4 * hi) = o;
    }
}

extern "C" void kernel_launch(void* const* d_in, const int* in_sizes, int n_in,
                              void* d_out, int out_size, void* d_ws, size_t ws_size,
                              hipStream_t stream) {
  const float* x    = (const float*)d_in[0];
  // d_in[1] = mask (recomputed analytically)
  const float* cosb = (const float*)d_in[2];
  const float* sinb = (const float*)d_in[3];
  const float* Wq   = (const float*)d_in[4];
  const float* Wk   = (const float*)d_in[5];
  const float* Wv   = (const float*)d_in[6];
  const float* Wo   = (const float*)d_in[7];
  const float* qsc  = (const float*)d_in[8];
  const float* ksc  = (const float*)d_in[9];
  float* out = (float*)d_out;

  char* ws = (char*)d_ws;
  const size_t MB = 1ull << 20;
  // [0,16)  xh fp16         -> after gemm0 reused: ctxf fp16
  // [16,28) wqkvT fp16      -> after gemm0 reused: kf[16,20) vtb[24,28)
  // [28,36) woT fp16
  // [36,60) qkv fp16
  f16* xh    = (f16*)(ws + 0 * MB);
  f16* ctxf  = (f16*)(ws + 0 * MB);
  f16* wqkvT = (f16*)(ws + 16 * MB);
  f16* kf    = (f16*)(ws + 16 * MB);
  f16* vtb   = (f16*)(ws + 24 * MB);
  f16* woT   = (f16*)(ws + 28 * MB);
  f16* qkvh  = (f16*)(ws + 36 * MB);

  prep<<<dim3(14336), 256, 0, stream>>>(x, xh, Wq, Wk, Wv, Wo, wqkvT, woT);
  gemm_f16<f16><<<dim3(NQKV_ / 128, M_ / 128), 256, 0, stream>>>(
      xh, wqkvT, qkvh, M_, NQKV_, D_);
  norm_kv<<<dim3(4608), 256, 0, stream>>>(qkvh, cosb, sinb, ksc, kf, vtb);
  flash_attn<<<dim3((S_ / QBLK) * H_ * B_), 256, 0, stream>>>(
      qkvh, cosb, sinb, qsc, kf, vtb, ctxf);
  gemm_f16<float><<<dim3(D_ / 128, M_ / 128), 256, 0, stream>>>(
      ctxf, woT, out, M_, D_, D_);
}